// Round 1
// 7998.310 us; speedup vs baseline: 1.3132x; 1.3132x over previous
//
#include <hip/hip_runtime.h>

typedef __bf16 bf16;
typedef __bf16 bf16x8 __attribute__((ext_vector_type(8)));
typedef float f32x4 __attribute__((ext_vector_type(4)));

#define EMBED 768
#define HEADS 12
#define DEPTH 12
#define B_ 256
#define F_ 4
#define L_ 20
#define NTOK 81              // 1 + F_*L_
#define ROWS (B_ * NTOK)     // 20736
#define SROWS (B_ * F_ * L_) // 20480

// async global->LDS, 16B per lane; LDS dst is wave-uniform base + lane*16
#define GLOAD16(g, l)                                                              \
    __builtin_amdgcn_global_load_lds((const __attribute__((address_space(1))) void*)(g), \
                                     (__attribute__((address_space(3))) void*)(l), 16, 0, 0)

// ---------------------------------------------------------------------------
// Repack + convert x[..., :2048] (f32, lda=2054) -> contiguous bf16 (20480,2048)
// ---------------------------------------------------------------------------
__global__ __launch_bounds__(256) void repack_kernel(const float* __restrict__ x,
                                                     bf16* __restrict__ xr) {
    int row = blockIdx.x;
    const float* src = x + (size_t)row * 2054;
    bf16* dst = xr + (size_t)row * 2048;
    int t = threadIdx.x;
    int e0 = t * 8;
    bf16 tmp[8];
#pragma unroll
    for (int i = 0; i < 4; ++i) {
        float2 v = *(const float2*)&src[e0 + 2 * i];
        tmp[2 * i] = (bf16)v.x;
        tmp[2 * i + 1] = (bf16)v.y;
    }
    *(uint4*)&dst[e0] = *(const uint4*)tmp;
}

// ---------------------------------------------------------------------------
// Weight convert f32 -> bf16, 8 elems/thread
// ---------------------------------------------------------------------------
__global__ __launch_bounds__(256) void w2bf_kernel(const float* __restrict__ src,
                                                   bf16* __restrict__ dst) {
    size_t i = ((size_t)blockIdx.x * 256 + threadIdx.x) * 8;
    float4 a = *(const float4*)&src[i];
    float4 b = *(const float4*)&src[i + 4];
    bf16 t[8] = {(bf16)a.x, (bf16)a.y, (bf16)a.z, (bf16)a.w,
                 (bf16)b.x, (bf16)b.y, (bf16)b.z, (bf16)b.w};
    *(uint4*)&dst[i] = *(const uint4*)t;
}

// ---------------------------------------------------------------------------
// GEMM (bf16 A, bf16 W): C[M,N] = A[M,K] @ W[N,K]^T + bias, fp32 accum.
// m97-structure: BK=64, global_load_lds width-16 for both operands, XOR-swizzled
// LDS (swizzle applied on the GLOBAL source address, linear LDS dest, swizzled
// ds_read). Tile 128x128, 256 threads (4 waves, 2x2), mfma_f32_16x16x32_bf16.
// Grid: (N/128, M/128)  -> co-resident blocks sweep shared A panels.
// FUSE: 0 none, 1 exact-gelu, 2 add residual R(bf16). ROWMAP: skip cls rows.
// ---------------------------------------------------------------------------
template <int FUSE, bool ROWMAP, typename CT>
__global__ __launch_bounds__(256) void gemm_bb(const bf16* __restrict__ A, int lda,
                                               const bf16* __restrict__ W,
                                               const float* __restrict__ bias,
                                               const bf16* __restrict__ R,
                                               CT* __restrict__ C, int N, int K) {
    __shared__ __align__(16) bf16 As[128 * 64];
    __shared__ __align__(16) bf16 Ws[128 * 64];

    const int tid = threadIdx.x;
    const int lane = tid & 63;
    const int wv = tid >> 6;
    const int wm = (wv & 1) * 64;
    const int wn = (wv >> 1) * 64;
    const int lr = lane & 15;
    const int lq = lane >> 4;
    const int n0 = blockIdx.x * 128;
    const int m0 = blockIdx.y * 128;

    // Staging lane geometry. LDS linear offset o = chunk*1024 + lane*16 bytes;
    // row = o>>7, colbyte = o&127. We want LDS[o] = tile[row][colbyte ^ ((row&7)<<4)]
    // so reads at swizzled addresses land conflict-free. row&7 == lane>>3 here.
    const int srow = lane >> 3;                 // row within 8-row chunk
    const int scol = 8 * ((lane & 7) ^ srow);   // pre-swizzled element col
    const bf16* aB = A + (size_t)(m0 + srow) * lda + scol;
    const bf16* wB = W + (size_t)(n0 + srow) * K + scol;

    f32x4 acc[4][4];
#pragma unroll
    for (int i = 0; i < 4; ++i)
#pragma unroll
        for (int j = 0; j < 4; ++j) acc[i][j] = (f32x4){0.f, 0.f, 0.f, 0.f};

    const int swz = (lr & 7) << 4;

    for (int k0 = 0; k0 < K; k0 += 64) {
        // 16 chunks of 1KB per tile; wave wv stages chunks [wv*4, wv*4+4) of each
#pragma unroll
        for (int i = 0; i < 4; ++i) {
            const int ch = wv * 4 + i;
            GLOAD16(aB + (size_t)(ch * 8) * lda + k0, &As[ch * 512]);
            GLOAD16(wB + (size_t)(ch * 8) * K + k0, &Ws[ch * 512]);
        }
        __syncthreads();  // compiler emits vmcnt(0) drain before s_barrier
#pragma unroll
        for (int kk = 0; kk < 2; ++kk) {
            // swizzled read: colbyte = (kk*64 | lq*16) ^ ((row&7)<<4); row&7 == lr&7
            const int co = (((kk << 6) | (lq << 4)) ^ swz) >> 1;
            bf16x8 af[4], bw[4];
#pragma unroll
            for (int t = 0; t < 4; ++t) {
                af[t] = *(const bf16x8*)&As[(wm + t * 16 + lr) * 64 + co];
                bw[t] = *(const bf16x8*)&Ws[(wn + t * 16 + lr) * 64 + co];
            }
#pragma unroll
            for (int mi = 0; mi < 4; ++mi)
#pragma unroll
                for (int ni = 0; ni < 4; ++ni)
                    acc[mi][ni] = __builtin_amdgcn_mfma_f32_16x16x32_bf16(af[mi], bw[ni],
                                                                          acc[mi][ni], 0, 0, 0);
        }
        __syncthreads();
    }

#pragma unroll
    for (int mi = 0; mi < 4; ++mi) {
#pragma unroll
        for (int ni = 0; ni < 4; ++ni) {
            int gcol = n0 + wn + ni * 16 + lr;
            float bv = bias ? bias[gcol] : 0.f;
#pragma unroll
            for (int r = 0; r < 4; ++r) {
                int grow = m0 + wm + mi * 16 + lq * 4 + r;
                float v = acc[mi][ni][r] + bv;
                if (FUSE == 1) v = 0.5f * v * (1.f + erff(v * 0.70710678118654752f));
                if (FUSE == 2) v += (float)R[(size_t)grow * N + gcol];
                int orow = grow;
                if (ROWMAP) orow = grow + grow / 80 + 1;  // skip cls rows
                C[(size_t)orow * N + gcol] = (CT)v;
            }
        }
    }
}

// ---------------------------------------------------------------------------
// Fallback GEMM (f32 W converted in-kernel) — used only if workspace too small
// ---------------------------------------------------------------------------
template <int FUSE, bool ROWMAP, typename CT>
__global__ __launch_bounds__(256) void gemm_bt(const bf16* __restrict__ A, int lda,
                                               const float* __restrict__ W,
                                               const float* __restrict__ bias,
                                               const bf16* __restrict__ R,
                                               CT* __restrict__ C, int N, int K) {
    __shared__ __align__(16) bf16 As[128][32];
    __shared__ __align__(16) bf16 Ws[128][32];

    const int tid = threadIdx.x;
    const int lane = tid & 63;
    const int wv = tid >> 6;
    const int wm = (wv & 1) * 64;
    const int wn = (wv >> 1) * 64;
    const int lr = lane & 15;
    const int lq = lane >> 4;
    const int m0 = blockIdx.x * 128;
    const int n0 = blockIdx.y * 128;

    f32x4 acc[4][4];
#pragma unroll
    for (int i = 0; i < 4; ++i)
#pragma unroll
        for (int j = 0; j < 4; ++j) acc[i][j] = (f32x4){0.f, 0.f, 0.f, 0.f};

    for (int k0 = 0; k0 < K; k0 += 32) {
#pragma unroll
        for (int i = 0; i < 2; ++i) {
            int c = tid + 256 * i;
            int row = c >> 2;
            int kc = (c & 3) * 8;
            *(uint4*)&As[row][kc] = *(const uint4*)&A[(size_t)(m0 + row) * lda + k0 + kc];
        }
#pragma unroll
        for (int i = 0; i < 4; ++i) {
            int c = tid + 256 * i;
            int row = c >> 3;
            int kc = (c & 7) * 4;
            float4 v = *(const float4*)&W[(size_t)(n0 + row) * K + k0 + kc];
            bf16 wb[4] = {(bf16)v.x, (bf16)v.y, (bf16)v.z, (bf16)v.w};
            *(uint2*)&Ws[row][kc] = *(const uint2*)wb;
        }
        __syncthreads();
        bf16x8 af[4], bf_[4];
#pragma unroll
        for (int t = 0; t < 4; ++t) {
            af[t] = *(const bf16x8*)&As[wm + t * 16 + lr][lq * 8];
            bf_[t] = *(const bf16x8*)&Ws[wn + t * 16 + lr][lq * 8];
        }
#pragma unroll
        for (int mi = 0; mi < 4; ++mi)
#pragma unroll
            for (int ni = 0; ni < 4; ++ni)
                acc[mi][ni] = __builtin_amdgcn_mfma_f32_16x16x32_bf16(af[mi], bf_[ni],
                                                                      acc[mi][ni], 0, 0, 0);
        __syncthreads();
    }

#pragma unroll
    for (int mi = 0; mi < 4; ++mi) {
#pragma unroll
        for (int ni = 0; ni < 4; ++ni) {
            int gcol = n0 + wn + ni * 16 + lr;
            float bv = bias ? bias[gcol] : 0.f;
#pragma unroll
            for (int r = 0; r < 4; ++r) {
                int grow = m0 + wm + mi * 16 + lq * 4 + r;
                float v = acc[mi][ni][r] + bv;
                if (FUSE == 1) v = 0.5f * v * (1.f + erff(v * 0.70710678118654752f));
                if (FUSE == 2) v += (float)R[(size_t)grow * N + gcol];
                int orow = grow;
                if (ROWMAP) orow = grow + grow / 80 + 1;
                C[(size_t)orow * N + gcol] = (CT)v;
            }
        }
    }
}

// ---------------------------------------------------------------------------
// Embed finish: add pos (K=6, f32) + pos_b + temporal_embed into tok (bf16)
// ---------------------------------------------------------------------------
__global__ __launch_bounds__(256) void embed_finish(const float* __restrict__ x,
                                                    const float* __restrict__ posW,
                                                    const float* __restrict__ posb,
                                                    const float* __restrict__ temb,
                                                    bf16* __restrict__ tok) {
    int r = blockIdx.x;  // 0..20479
    int fr = (r % 80) / 20;
    int orow = r + r / 80 + 1;
    __shared__ float pf[6];
    if (threadIdx.x < 6) pf[threadIdx.x] = x[(size_t)r * 2054 + 2048 + threadIdx.x];
    __syncthreads();
    int t = threadIdx.x;
#pragma unroll
    for (int i = 0; i < 3; ++i) {
        int c = t + 256 * i;
        float v = posb[c] + temb[fr * EMBED + c];
#pragma unroll
        for (int j = 0; j < 6; ++j) v += pf[j] * posW[c * 6 + j];
        size_t idx = (size_t)orow * EMBED + c;
        tok[idx] = (bf16)((float)tok[idx] + v);
    }
}

// ---------------------------------------------------------------------------
// cls rows (bf16 tok) + mbias (f32 scratch) + output 1 (f32)
// ---------------------------------------------------------------------------
__global__ __launch_bounds__(256) void cls_mbias_kernel(const float* __restrict__ cls_tok,
                                                        const float* __restrict__ cls_pos,
                                                        const int* __restrict__ xmask,
                                                        bf16* __restrict__ tok,
                                                        float* __restrict__ mbias,
                                                        float* __restrict__ out1) {
    int b = blockIdx.x;
    int t = threadIdx.x;
#pragma unroll
    for (int i = 0; i < 3; ++i) {
        int c = t + 256 * i;
        tok[(size_t)(b * NTOK) * EMBED + c] = (bf16)(cls_tok[c] + cls_pos[c]);
    }
    if (t < NTOK) {
        float mv = (t == 0) ? 0.f : ((float)xmask[b * 80 + t - 1] - 1.f) * 100.f;
        mbias[b * NTOK + t] = mv;
        out1[b * NTOK + t] = mv;
    }
}

// ---------------------------------------------------------------------------
// LayerNorm: one block per row, 768 cols, fp32 stats, eps=1e-6. w/b f32.
// ---------------------------------------------------------------------------
__global__ __launch_bounds__(256) void ln_kernel(const bf16* __restrict__ X,
                                                 const float* __restrict__ w,
                                                 const float* __restrict__ b,
                                                 bf16* __restrict__ Y) {
    int row = blockIdx.x;
    const bf16* xr = X + (size_t)row * EMBED;
    int t = threadIdx.x;
    float xv[3], s = 0.f, ss = 0.f;
#pragma unroll
    for (int i = 0; i < 3; ++i) {
        float v = (float)xr[t + 256 * i];
        xv[i] = v;
        s += v;
        ss += v * v;
    }
#pragma unroll
    for (int off = 32; off; off >>= 1) {
        s += __shfl_down(s, off);
        ss += __shfl_down(ss, off);
    }
    __shared__ float ws_s[4], ws_q[4];
    int wv = t >> 6, lane = t & 63;
    if (lane == 0) { ws_s[wv] = s; ws_q[wv] = ss; }
    __syncthreads();
    s = ws_s[0] + ws_s[1] + ws_s[2] + ws_s[3];
    ss = ws_q[0] + ws_q[1] + ws_q[2] + ws_q[3];
    float mean = s * (1.f / 768.f);
    float var = ss * (1.f / 768.f) - mean * mean;
    float inv = rsqrtf(fmaxf(var, 0.f) + 1e-6f);
#pragma unroll
    for (int i = 0; i < 3; ++i) {
        int c = t + 256 * i;
        Y[(size_t)row * EMBED + c] = (bf16)((xv[i] - mean) * inv * w[c] + b[c]);
    }
}

// ---------------------------------------------------------------------------
// Frame-local attention. One block per (batch, head). N=81, d=64, f=4, n=20.
// ---------------------------------------------------------------------------
__global__ __launch_bounds__(256) void attn_kernel(const bf16* __restrict__ qkv,
                                                   const float* __restrict__ mbias,
                                                   bf16* __restrict__ aout) {
    int bh = blockIdx.x;
    int b = bh / HEADS, h = bh % HEADS;
    __shared__ bf16 Qs[NTOK][66], Ks[NTOK][66], Vs[NTOK][66];
    __shared__ float S[80][21];
    __shared__ float Sc[NTOK];
    __shared__ float MB[NTOK];
    const size_t base = (size_t)(b * NTOK) * 2304 + h * 64;
    int t = threadIdx.x;
    for (int e = t; e < NTOK * 64; e += 256) {
        int r = e >> 6, c = e & 63;
        size_t o = base + (size_t)r * 2304 + c;
        Qs[r][c] = (bf16)((float)qkv[o] * 0.125f);
        Ks[r][c] = qkv[o + 768];
        Vs[r][c] = qkv[o + 1536];
    }
    if (t < NTOK) MB[t] = mbias[b * NTOK + t];
    __syncthreads();
    for (int j = t; j < 80 * 21 + NTOK; j += 256) {
        if (j < 1680) {
            int qi = j / 21, kj = j % 21;
            int qt = 1 + qi;
            int kt = (kj == 0) ? 0 : (qi / 20) * 20 + kj;
            float sv = 0.f;
            for (int c = 0; c < 64; ++c) sv += (float)Qs[qt][c] * (float)Ks[kt][c];
            S[qi][kj] = sv + MB[kt];
        } else {
            int kt = j - 1680;
            float sv = 0.f;
            for (int c = 0; c < 64; ++c) sv += (float)Qs[0][c] * (float)Ks[kt][c];
            Sc[kt] = sv + MB[kt];
        }
    }
    __syncthreads();
    if (t < 80) {
        float mx = -1e30f;
        for (int j = 0; j < 21; ++j) mx = fmaxf(mx, S[t][j]);
        float sum = 0.f;
        for (int j = 0; j < 21; ++j) { float e = __expf(S[t][j] - mx); S[t][j] = e; sum += e; }
        float rs = 1.f / sum;
        for (int j = 0; j < 21; ++j) S[t][j] *= rs;
    } else if (t == 80) {
        float mx = -1e30f;
        for (int j = 0; j < NTOK; ++j) mx = fmaxf(mx, Sc[j]);
        float sum = 0.f;
        for (int j = 0; j < NTOK; ++j) { float e = __expf(Sc[j] - mx); Sc[j] = e; sum += e; }
        float rs = 1.f / sum;
        for (int j = 0; j < NTOK; ++j) Sc[j] *= rs;
    }
    __syncthreads();
    for (int e = t; e < NTOK * 64; e += 256) {
        int r = e >> 6, c = e & 63;
        float o = 0.f;
        if (r == 0) {
            for (int j = 0; j < NTOK; ++j) o += Sc[j] * (float)Vs[j][c];
        } else {
            int qi = r - 1, fb = (qi / 20) * 20;
            o += S[qi][0] * (float)Vs[0][c];
            for (int j = 1; j < 21; ++j) o += S[qi][j] * (float)Vs[fb + j][c];
        }
        aout[(size_t)(b * NTOK + r) * EMBED + h * 64 + c] = (bf16)o;
    }
}

// ---------------------------------------------------------------------------
extern "C" void kernel_launch(void* const* d_in, const int* in_sizes, int n_in,
                              void* d_out, int out_size, void* d_ws, size_t ws_size,
                              hipStream_t stream) {
    const float* x = (const float*)d_in[0];
    const int* xmask = (const int*)d_in[1];
    const float* objW = (const float*)d_in[2];
    const float* objb = (const float*)d_in[3];
    const float* posW = (const float*)d_in[4];
    const float* posb = (const float*)d_in[5];
    const float* clsT = (const float*)d_in[6];
    const float* clsP = (const float*)d_in[7];
    const float* temb = (const float*)d_in[8];
    const float* ln1w = (const float*)d_in[9];
    const float* ln1b = (const float*)d_in[10];
    const float* ln2w = (const float*)d_in[11];
    const float* ln2b = (const float*)d_in[12];
    const float* qkvW = (const float*)d_in[13];
    const float* qkvb = (const float*)d_in[14];
    const float* apW = (const float*)d_in[15];
    const float* apb = (const float*)d_in[16];
    const float* f1W = (const float*)d_in[17];
    const float* f1b = (const float*)d_in[18];
    const float* f2W = (const float*)d_in[19];
    const float* f2b = (const float*)d_in[20];
    const float* projW = (const float*)d_in[21];

    char* ws = (char*)d_ws;
    bf16* tok = (bf16*)(ws);                              // 30.4 MiB
    bf16* s1 = (bf16*)(ws + (size_t)(32 << 20));          // 30.4 MiB (ln out / attn out)
    float* mb = (float*)(ws + (size_t)(64 << 20));        // 83 KB
    bf16* big = (bf16*)(ws + (size_t)(65 << 20));         // up to 121.5 MiB (xr/qkv/hidden)
    float* out0 = (float*)d_out;
    float* out1 = out0 + (size_t)ROWS * 256;

    // bf16 weight cache layout (starts above `big`'s end at ~186.5 MiB)
    const size_t WOFF = (size_t)192 << 20;
    const size_t E_OBJ = (size_t)768 * 2048;          //  1,572,864
    const size_t E_QKV = (size_t)DEPTH * 2304 * 768;  // 21,233,664
    const size_t E_AP = (size_t)DEPTH * 768 * 768;    //  7,077,888
    const size_t E_FC = (size_t)DEPTH * 3072 * 768;   // 28,311,552 (fc1 and fc2)
    const size_t E_PROJ = (size_t)256 * 768;          //    196,608
    const size_t WTOT = (E_OBJ + E_QKV + E_AP + 2 * E_FC + E_PROJ) * 2;
    const bool bigws = ws_size >= WOFF + WTOT;

    if (bigws) {
        bf16* objW16 = (bf16*)(ws + WOFF);
        bf16* qkvW16 = objW16 + E_OBJ;
        bf16* apW16 = qkvW16 + E_QKV;
        bf16* fc1W16 = apW16 + E_AP;
        bf16* fc2W16 = fc1W16 + E_FC;
        bf16* projW16 = fc2W16 + E_FC;

        // one-shot weight conversion (grid = elems/2048, all exact)
        w2bf_kernel<<<(int)(E_OBJ / 2048), 256, 0, stream>>>(objW, objW16);
        w2bf_kernel<<<(int)(E_QKV / 2048), 256, 0, stream>>>(qkvW, qkvW16);
        w2bf_kernel<<<(int)(E_AP / 2048), 256, 0, stream>>>(apW, apW16);
        w2bf_kernel<<<(int)(E_FC / 2048), 256, 0, stream>>>(f1W, fc1W16);
        w2bf_kernel<<<(int)(E_FC / 2048), 256, 0, stream>>>(f2W, fc2W16);
        w2bf_kernel<<<(int)(E_PROJ / 2048), 256, 0, stream>>>(projW, projW16);

        // Embedding
        repack_kernel<<<SROWS, 256, 0, stream>>>(x, big);
        gemm_bb<0, true, bf16><<<dim3(EMBED / 128, SROWS / 128), 256, 0, stream>>>(
            big, 2048, objW16, objb, nullptr, tok, EMBED, 2048);
        embed_finish<<<SROWS, 256, 0, stream>>>(x, posW, posb, temb, tok);
        cls_mbias_kernel<<<B_, 256, 0, stream>>>(clsT, clsP, xmask, tok, mb, out1);

        // Transformer layers
        for (int l = 0; l < DEPTH; ++l) {
            ln_kernel<<<ROWS, 256, 0, stream>>>(tok, ln1w + l * EMBED, ln1b + l * EMBED, s1);
            gemm_bb<0, false, bf16><<<dim3(2304 / 128, ROWS / 128), 256, 0, stream>>>(
                s1, EMBED, qkvW16 + (size_t)l * 2304 * 768, qkvb + l * 2304, nullptr, big,
                2304, EMBED);
            attn_kernel<<<B_ * HEADS, 256, 0, stream>>>(big, mb, s1);
            gemm_bb<2, false, bf16><<<dim3(EMBED / 128, ROWS / 128), 256, 0, stream>>>(
                s1, EMBED, apW16 + (size_t)l * 768 * 768, apb + l * EMBED, tok, tok, EMBED,
                EMBED);
            ln_kernel<<<ROWS, 256, 0, stream>>>(tok, ln2w + l * EMBED, ln2b + l * EMBED, s1);
            gemm_bb<1, false, bf16><<<dim3(3072 / 128, ROWS / 128), 256, 0, stream>>>(
                s1, EMBED, fc1W16 + (size_t)l * 3072 * 768, f1b + l * 3072, nullptr, big,
                3072, EMBED);
            gemm_bb<2, false, bf16><<<dim3(EMBED / 128, ROWS / 128), 256, 0, stream>>>(
                big, 3072, fc2W16 + (size_t)l * 3072 * 768, f2b + l * EMBED, tok, tok, EMBED,
                3072);
        }

        // Final projection (no bias), f32 output
        gemm_bb<0, false, float><<<dim3(256 / 128, ROWS / 128), 256, 0, stream>>>(
            tok, EMBED, projW16, nullptr, nullptr, out0, 256, EMBED);
    } else {
        // -------- fallback: previous (f32-weight) path --------
        repack_kernel<<<SROWS, 256, 0, stream>>>(x, big);
        gemm_bt<0, true, bf16><<<dim3(SROWS / 128, EMBED / 128), 256, 0, stream>>>(
            big, 2048, objW, objb, nullptr, tok, EMBED, 2048);
        embed_finish<<<SROWS, 256, 0, stream>>>(x, posW, posb, temb, tok);
        cls_mbias_kernel<<<B_, 256, 0, stream>>>(clsT, clsP, xmask, tok, mb, out1);

        for (int l = 0; l < DEPTH; ++l) {
            ln_kernel<<<ROWS, 256, 0, stream>>>(tok, ln1w + l * EMBED, ln1b + l * EMBED, s1);
            gemm_bt<0, false, bf16><<<dim3(ROWS / 128, 2304 / 128), 256, 0, stream>>>(
                s1, EMBED, qkvW + (size_t)l * 2304 * EMBED, qkvb + l * 2304, nullptr, big,
                2304, EMBED);
            attn_kernel<<<B_ * HEADS, 256, 0, stream>>>(big, mb, s1);
            gemm_bt<2, false, bf16><<<dim3(ROWS / 128, EMBED / 128), 256, 0, stream>>>(
                s1, EMBED, apW + (size_t)l * EMBED * EMBED, apb + l * EMBED, tok, tok, EMBED,
                EMBED);
            ln_kernel<<<ROWS, 256, 0, stream>>>(tok, ln2w + l * EMBED, ln2b + l * EMBED, s1);
            gemm_bt<1, false, bf16><<<dim3(ROWS / 128, 3072 / 128), 256, 0, stream>>>(
                s1, EMBED, f1W + (size_t)l * 3072 * EMBED, f1b + l * 3072, nullptr, big, 3072,
                EMBED);
            gemm_bt<2, false, bf16><<<dim3(ROWS / 128, EMBED / 128), 256, 0, stream>>>(
                big, 3072, f2W + (size_t)l * EMBED * 3072, f2b + l * EMBED, tok, tok, EMBED,
                3072);
        }

        gemm_bt<0, false, float><<<dim3(ROWS / 128, 256 / 128), 256, 0, stream>>>(
            tok, EMBED, projW, nullptr, nullptr, out0, 256, EMBED);
    }
}

// Round 2
// 7552.306 us; speedup vs baseline: 1.3907x; 1.0591x over previous
//
#include <hip/hip_runtime.h>

typedef __bf16 bf16;
typedef __bf16 bf16x8 __attribute__((ext_vector_type(8)));
typedef float f32x4 __attribute__((ext_vector_type(4)));

#define EMBED 768
#define HEADS 12
#define DEPTH 12
#define B_ 256
#define F_ 4
#define L_ 20
#define NTOK 81              // 1 + F_*L_
#define ROWS (B_ * NTOK)     // 20736
#define SROWS (B_ * F_ * L_) // 20480

// async global->LDS, 16B per lane; LDS dst is wave-uniform base + lane*16
#define GLOAD16(g, l)                                                              \
    __builtin_amdgcn_global_load_lds((const __attribute__((address_space(1))) void*)(g), \
                                     (__attribute__((address_space(3))) void*)(l), 16, 0, 0)

// Fast exact-gelu: Abramowitz-Stegun 7.1.26 erf, |err| <= 1.5e-7 (<< bf16 ulp)
__device__ __forceinline__ float fast_gelu(float v) {
    float x = v * 0.70710678118654752f;
    float ax = fabsf(x);
    float t = __fdividef(1.f, fmaf(0.3275911f, ax, 1.f));
    float p = ((((1.061405429f * t - 1.453152027f) * t + 1.421413741f) * t -
                0.284496736f) * t + 0.254829592f) * t;
    float e = __expf(-ax * ax);
    float erfv = copysignf(1.f - p * e, x);
    return 0.5f * v * (1.f + erfv);
}

// ---------------------------------------------------------------------------
// Repack + convert x[..., :2048] (f32, lda=2054) -> contiguous bf16 (20480,2048)
// ---------------------------------------------------------------------------
__global__ __launch_bounds__(256) void repack_kernel(const float* __restrict__ x,
                                                     bf16* __restrict__ xr) {
    int row = blockIdx.x;
    const float* src = x + (size_t)row * 2054;
    bf16* dst = xr + (size_t)row * 2048;
    int t = threadIdx.x;
    int e0 = t * 8;
    bf16 tmp[8];
#pragma unroll
    for (int i = 0; i < 4; ++i) {
        float2 v = *(const float2*)&src[e0 + 2 * i];
        tmp[2 * i] = (bf16)v.x;
        tmp[2 * i + 1] = (bf16)v.y;
    }
    *(uint4*)&dst[e0] = *(const uint4*)tmp;
}

// ---------------------------------------------------------------------------
// Weight convert f32 -> bf16, 8 elems/thread
// ---------------------------------------------------------------------------
__global__ __launch_bounds__(256) void w2bf_kernel(const float* __restrict__ src,
                                                   bf16* __restrict__ dst) {
    size_t i = ((size_t)blockIdx.x * 256 + threadIdx.x) * 8;
    float4 a = *(const float4*)&src[i];
    float4 b = *(const float4*)&src[i + 4];
    bf16 t[8] = {(bf16)a.x, (bf16)a.y, (bf16)a.z, (bf16)a.w,
                 (bf16)b.x, (bf16)b.y, (bf16)b.z, (bf16)b.w};
    *(uint4*)&dst[i] = *(const uint4*)t;
}

// ---------------------------------------------------------------------------
// GEMM (bf16 A, bf16 W): C[M,N] = A[M,K] @ W[N,K]^T + bias, fp32 accum.
// m97-structure: BK=64, global_load_lds width-16, XOR-swizzled LDS (swizzle on
// the GLOBAL source address, linear LDS dest, swizzled ds_read). Tile 128x128,
// 256 threads (4 waves, 2x2), mfma_f32_16x16x32_bf16. Bijective XCD-chunked
// block swizzle (m204) so blocks sharing an A-panel land on one XCD's L2.
// FUSE: 0 none, 1 exact-gelu, 2 add residual R(bf16). ROWMAP: skip cls rows.
// ---------------------------------------------------------------------------
template <int FUSE, bool ROWMAP, typename CT>
__global__ __launch_bounds__(256) void gemm_bb(const bf16* __restrict__ A, int lda,
                                               const bf16* __restrict__ W,
                                               const float* __restrict__ bias,
                                               const bf16* __restrict__ R,
                                               CT* __restrict__ C, int N, int K) {
    __shared__ __align__(16) bf16 As[128 * 64];
    __shared__ __align__(16) bf16 Ws[128 * 64];

    const int tid = threadIdx.x;
    const int lane = tid & 63;
    const int wv = tid >> 6;
    const int wm = (wv & 1) * 64;
    const int wn = (wv >> 1) * 64;
    const int lr = lane & 15;
    const int lq = lane >> 4;

    // bijective XCD-chunked swizzle: consecutive remapped ids stay on one XCD
    const int GX = gridDim.x;
    const int nwg = GX * gridDim.y;
    const int flat = blockIdx.y * GX + blockIdx.x;
    const int xcd = flat & 7, pos = flat >> 3;
    const int qc = nwg >> 3, rc = nwg & 7;
    const int wg = (xcd < rc ? xcd * (qc + 1) : rc * (qc + 1) + (xcd - rc) * qc) + pos;
    const int n0 = (wg % GX) * 128;
    const int m0 = (wg / GX) * 128;

    // Staging lane geometry. LDS linear offset o = chunk*1024 + lane*16 bytes;
    // row = o>>7, colbyte = o&127. We want LDS[o] = tile[row][colbyte ^ ((row&7)<<4)]
    // so reads at swizzled addresses land conflict-free. row&7 == lane>>3 here.
    const int srow = lane >> 3;                 // row within 8-row chunk
    const int scol = 8 * ((lane & 7) ^ srow);   // pre-swizzled element col
    const bf16* aB = A + (size_t)(m0 + srow) * lda + scol;
    const bf16* wB = W + (size_t)(n0 + srow) * K + scol;

    f32x4 acc[4][4];
#pragma unroll
    for (int i = 0; i < 4; ++i)
#pragma unroll
        for (int j = 0; j < 4; ++j) acc[i][j] = (f32x4){0.f, 0.f, 0.f, 0.f};

    const int swz = (lr & 7) << 4;

    for (int k0 = 0; k0 < K; k0 += 64) {
        // 16 chunks of 1KB per tile; wave wv stages chunks [wv*4, wv*4+4) of each
#pragma unroll
        for (int i = 0; i < 4; ++i) {
            const int ch = wv * 4 + i;
            GLOAD16(aB + (size_t)(ch * 8) * lda + k0, &As[ch * 512]);
            GLOAD16(wB + (size_t)(ch * 8) * K + k0, &Ws[ch * 512]);
        }
        __syncthreads();  // compiler emits vmcnt(0) drain before s_barrier
#pragma unroll
        for (int kk = 0; kk < 2; ++kk) {
            // swizzled read: colbyte = (kk*64 | lq*16) ^ ((row&7)<<4); row&7 == lr&7
            const int co = (((kk << 6) | (lq << 4)) ^ swz) >> 1;
            bf16x8 af[4], bw[4];
#pragma unroll
            for (int t = 0; t < 4; ++t) {
                af[t] = *(const bf16x8*)&As[(wm + t * 16 + lr) * 64 + co];
                bw[t] = *(const bf16x8*)&Ws[(wn + t * 16 + lr) * 64 + co];
            }
#pragma unroll
            for (int mi = 0; mi < 4; ++mi)
#pragma unroll
                for (int ni = 0; ni < 4; ++ni)
                    acc[mi][ni] = __builtin_amdgcn_mfma_f32_16x16x32_bf16(af[mi], bw[ni],
                                                                          acc[mi][ni], 0, 0, 0);
        }
        __syncthreads();
    }

#pragma unroll
    for (int mi = 0; mi < 4; ++mi) {
#pragma unroll
        for (int ni = 0; ni < 4; ++ni) {
            int gcol = n0 + wn + ni * 16 + lr;
            float bv = bias ? bias[gcol] : 0.f;
#pragma unroll
            for (int r = 0; r < 4; ++r) {
                int grow = m0 + wm + mi * 16 + lq * 4 + r;
                float v = acc[mi][ni][r] + bv;
                if (FUSE == 1) v = fast_gelu(v);
                if (FUSE == 2) v += (float)R[(size_t)grow * N + gcol];
                int orow = grow;
                if (ROWMAP) orow = grow + grow / 80 + 1;  // skip cls rows
                C[(size_t)orow * N + gcol] = (CT)v;
            }
        }
    }
}

// ---------------------------------------------------------------------------
// Fallback GEMM (f32 W converted in-kernel) — used only if workspace too small
// ---------------------------------------------------------------------------
template <int FUSE, bool ROWMAP, typename CT>
__global__ __launch_bounds__(256) void gemm_bt(const bf16* __restrict__ A, int lda,
                                               const float* __restrict__ W,
                                               const float* __restrict__ bias,
                                               const bf16* __restrict__ R,
                                               CT* __restrict__ C, int N, int K) {
    __shared__ __align__(16) bf16 As[128][32];
    __shared__ __align__(16) bf16 Ws[128][32];

    const int tid = threadIdx.x;
    const int lane = tid & 63;
    const int wv = tid >> 6;
    const int wm = (wv & 1) * 64;
    const int wn = (wv >> 1) * 64;
    const int lr = lane & 15;
    const int lq = lane >> 4;
    const int m0 = blockIdx.x * 128;
    const int n0 = blockIdx.y * 128;

    f32x4 acc[4][4];
#pragma unroll
    for (int i = 0; i < 4; ++i)
#pragma unroll
        for (int j = 0; j < 4; ++j) acc[i][j] = (f32x4){0.f, 0.f, 0.f, 0.f};

    for (int k0 = 0; k0 < K; k0 += 32) {
#pragma unroll
        for (int i = 0; i < 2; ++i) {
            int c = tid + 256 * i;
            int row = c >> 2;
            int kc = (c & 3) * 8;
            *(uint4*)&As[row][kc] = *(const uint4*)&A[(size_t)(m0 + row) * lda + k0 + kc];
        }
#pragma unroll
        for (int i = 0; i < 4; ++i) {
            int c = tid + 256 * i;
            int row = c >> 3;
            int kc = (c & 7) * 4;
            float4 v = *(const float4*)&W[(size_t)(n0 + row) * K + k0 + kc];
            bf16 wb[4] = {(bf16)v.x, (bf16)v.y, (bf16)v.z, (bf16)v.w};
            *(uint2*)&Ws[row][kc] = *(const uint2*)wb;
        }
        __syncthreads();
        bf16x8 af[4], bf_[4];
#pragma unroll
        for (int t = 0; t < 4; ++t) {
            af[t] = *(const bf16x8*)&As[wm + t * 16 + lr][lq * 8];
            bf_[t] = *(const bf16x8*)&Ws[wn + t * 16 + lr][lq * 8];
        }
#pragma unroll
        for (int mi = 0; mi < 4; ++mi)
#pragma unroll
            for (int ni = 0; ni < 4; ++ni)
                acc[mi][ni] = __builtin_amdgcn_mfma_f32_16x16x32_bf16(af[mi], bf_[ni],
                                                                      acc[mi][ni], 0, 0, 0);
        __syncthreads();
    }

#pragma unroll
    for (int mi = 0; mi < 4; ++mi) {
#pragma unroll
        for (int ni = 0; ni < 4; ++ni) {
            int gcol = n0 + wn + ni * 16 + lr;
            float bv = bias ? bias[gcol] : 0.f;
#pragma unroll
            for (int r = 0; r < 4; ++r) {
                int grow = m0 + wm + mi * 16 + lq * 4 + r;
                float v = acc[mi][ni][r] + bv;
                if (FUSE == 1) v = fast_gelu(v);
                if (FUSE == 2) v += (float)R[(size_t)grow * N + gcol];
                int orow = grow;
                if (ROWMAP) orow = grow + grow / 80 + 1;
                C[(size_t)orow * N + gcol] = (CT)v;
            }
        }
    }
}

// ---------------------------------------------------------------------------
// Embed finish: add pos (K=6, f32) + pos_b + temporal_embed into tok (bf16)
// ---------------------------------------------------------------------------
__global__ __launch_bounds__(256) void embed_finish(const float* __restrict__ x,
                                                    const float* __restrict__ posW,
                                                    const float* __restrict__ posb,
                                                    const float* __restrict__ temb,
                                                    bf16* __restrict__ tok) {
    int r = blockIdx.x;  // 0..20479
    int fr = (r % 80) / 20;
    int orow = r + r / 80 + 1;
    __shared__ float pf[6];
    if (threadIdx.x < 6) pf[threadIdx.x] = x[(size_t)r * 2054 + 2048 + threadIdx.x];
    __syncthreads();
    int t = threadIdx.x;
#pragma unroll
    for (int i = 0; i < 3; ++i) {
        int c = t + 256 * i;
        float v = posb[c] + temb[fr * EMBED + c];
#pragma unroll
        for (int j = 0; j < 6; ++j) v += pf[j] * posW[c * 6 + j];
        size_t idx = (size_t)orow * EMBED + c;
        tok[idx] = (bf16)((float)tok[idx] + v);
    }
}

// ---------------------------------------------------------------------------
// cls rows (bf16 tok) + mbias (f32 scratch) + output 1 (f32)
// ---------------------------------------------------------------------------
__global__ __launch_bounds__(256) void cls_mbias_kernel(const float* __restrict__ cls_tok,
                                                        const float* __restrict__ cls_pos,
                                                        const int* __restrict__ xmask,
                                                        bf16* __restrict__ tok,
                                                        float* __restrict__ mbias,
                                                        float* __restrict__ out1) {
    int b = blockIdx.x;
    int t = threadIdx.x;
#pragma unroll
    for (int i = 0; i < 3; ++i) {
        int c = t + 256 * i;
        tok[(size_t)(b * NTOK) * EMBED + c] = (bf16)(cls_tok[c] + cls_pos[c]);
    }
    if (t < NTOK) {
        float mv = (t == 0) ? 0.f : ((float)xmask[b * 80 + t - 1] - 1.f) * 100.f;
        mbias[b * NTOK + t] = mv;
        out1[b * NTOK + t] = mv;
    }
}

// ---------------------------------------------------------------------------
// LayerNorm: one block per row, 768 cols, fp32 stats, eps=1e-6. w/b f32.
// Vectorized: threads 0..95 each own one bf16x8 chunk.
// ---------------------------------------------------------------------------
__global__ __launch_bounds__(256) void ln_kernel(const bf16* __restrict__ X,
                                                 const float* __restrict__ w,
                                                 const float* __restrict__ b,
                                                 bf16* __restrict__ Y) {
    int row = blockIdx.x;
    int t = threadIdx.x;
    float xv[8];
    float s = 0.f, ss = 0.f;
    if (t < 96) {
        bf16x8 v8 = *(const bf16x8*)&X[(size_t)row * EMBED + t * 8];
#pragma unroll
        for (int i = 0; i < 8; ++i) {
            float v = (float)v8[i];
            xv[i] = v;
            s += v;
            ss += v * v;
        }
    }
#pragma unroll
    for (int off = 32; off; off >>= 1) {
        s += __shfl_down(s, off);
        ss += __shfl_down(ss, off);
    }
    __shared__ float ws_s[4], ws_q[4];
    int wv = t >> 6, lane = t & 63;
    if (lane == 0) { ws_s[wv] = s; ws_q[wv] = ss; }
    __syncthreads();
    s = ws_s[0] + ws_s[1];
    ss = ws_q[0] + ws_q[1];
    float mean = s * (1.f / 768.f);
    float var = ss * (1.f / 768.f) - mean * mean;
    float inv = rsqrtf(fmaxf(var, 0.f) + 1e-6f);
    if (t < 96) {
        float4 w0 = *(const float4*)&w[t * 8];
        float4 w1 = *(const float4*)&w[t * 8 + 4];
        float4 b0 = *(const float4*)&b[t * 8];
        float4 b1 = *(const float4*)&b[t * 8 + 4];
        float wr[8] = {w0.x, w0.y, w0.z, w0.w, w1.x, w1.y, w1.z, w1.w};
        float br[8] = {b0.x, b0.y, b0.z, b0.w, b1.x, b1.y, b1.z, b1.w};
        bf16 ob[8];
#pragma unroll
        for (int i = 0; i < 8; ++i) ob[i] = (bf16)((xv[i] - mean) * inv * wr[i] + br[i]);
        *(uint4*)&Y[(size_t)row * EMBED + t * 8] = *(const uint4*)ob;
    }
}

// ---------------------------------------------------------------------------
// Frame-local attention. One block per (batch, head). N=81, d=64, f=4, n=20.
// Vectorized: uint4 staging; K,Q as f32 in LDS; Q-row cached in registers;
// float4 dot inner loops; vectorized PV + stores.
// ---------------------------------------------------------------------------
__global__ __launch_bounds__(256) void attn_kernel(const bf16* __restrict__ qkv,
                                                   const float* __restrict__ mbias,
                                                   bf16* __restrict__ aout) {
    int bh = blockIdx.x;
    int b = bh / HEADS, h = bh % HEADS;
    __shared__ __align__(16) float Qf[NTOK][68];
    __shared__ __align__(16) float Kf[NTOK][68];
    __shared__ __align__(16) bf16 Vs[NTOK][72];
    __shared__ float S[80][22];
    __shared__ float Sc[96];
    __shared__ float MB[NTOK];
    const size_t base = (size_t)(b * NTOK) * 2304 + h * 64;
    int t = threadIdx.x;

    // stage: 81 rows x 8 chunks of 8 elems
    for (int ch = t; ch < NTOK * 8; ch += 256) {
        int r = ch >> 3, c8 = (ch & 7) * 8;
        size_t o = base + (size_t)r * 2304 + c8;
        bf16x8 qv = *(const bf16x8*)&qkv[o];
        bf16x8 kv = *(const bf16x8*)&qkv[o + 768];
        *(uint4*)&Vs[r][c8] = *(const uint4*)&qkv[o + 1536];
        float4 q0 = {(float)qv[0], (float)qv[1], (float)qv[2], (float)qv[3]};
        float4 q1 = {(float)qv[4], (float)qv[5], (float)qv[6], (float)qv[7]};
        float4 k0 = {(float)kv[0], (float)kv[1], (float)kv[2], (float)kv[3]};
        float4 k1 = {(float)kv[4], (float)kv[5], (float)kv[6], (float)kv[7]};
        *(float4*)&Qf[r][c8] = q0;
        *(float4*)&Qf[r][c8 + 4] = q1;
        *(float4*)&Kf[r][c8] = k0;
        *(float4*)&Kf[r][c8 + 4] = k1;
    }
    if (t < NTOK) MB[t] = mbias[b * NTOK + t];
    __syncthreads();

    // QK^T. threads 0..239: spatial (3 threads per q-row, 7 keys each);
    // threads 240..255: cls row (16 threads, ~5-6 keys each).
    {
        int qt, kst, kstep, klim;
        if (t < 240) {
            int qi = t / 3;
            qt = 1 + qi;
            kst = t - qi * 3;
            kstep = 3;
            klim = 21;
        } else {
            qt = 0;
            kst = t - 240;
            kstep = 16;
            klim = NTOK;
        }
        float fq[64];
#pragma unroll
        for (int i = 0; i < 16; ++i) {
            float4 v = *(const float4*)&Qf[qt][i * 4];
            fq[4 * i] = v.x; fq[4 * i + 1] = v.y; fq[4 * i + 2] = v.z; fq[4 * i + 3] = v.w;
        }
        if (t < 240) {
            int qi = t / 3, fb = (qi / 20) * 20;
            for (int kj = kst; kj < klim; kj += kstep) {
                int kt = (kj == 0) ? 0 : fb + kj;
                float acc = 0.f;
#pragma unroll
                for (int i = 0; i < 16; ++i) {
                    float4 kv = *(const float4*)&Kf[kt][i * 4];
                    acc += fq[4 * i] * kv.x + fq[4 * i + 1] * kv.y +
                           fq[4 * i + 2] * kv.z + fq[4 * i + 3] * kv.w;
                }
                S[qi][kj] = acc * 0.125f + MB[kt];
            }
        } else {
            for (int kt = kst; kt < klim; kt += kstep) {
                float acc = 0.f;
#pragma unroll
                for (int i = 0; i < 16; ++i) {
                    float4 kv = *(const float4*)&Kf[kt][i * 4];
                    acc += fq[4 * i] * kv.x + fq[4 * i + 1] * kv.y +
                           fq[4 * i + 2] * kv.z + fq[4 * i + 3] * kv.w;
                }
                Sc[kt] = acc * 0.125f + MB[kt];
            }
        }
    }
    __syncthreads();

    if (t < 80) {
        float mx = -1e30f;
        for (int j = 0; j < 21; ++j) mx = fmaxf(mx, S[t][j]);
        float sum = 0.f;
        for (int j = 0; j < 21; ++j) { float e = __expf(S[t][j] - mx); S[t][j] = e; sum += e; }
        float rs = 1.f / sum;
        for (int j = 0; j < 21; ++j) S[t][j] *= rs;
    } else if (t == 80) {
        float mx = -1e30f;
        for (int j = 0; j < NTOK; ++j) mx = fmaxf(mx, Sc[j]);
        float sum = 0.f;
        for (int j = 0; j < NTOK; ++j) { float e = __expf(Sc[j] - mx); Sc[j] = e; sum += e; }
        float rs = 1.f / sum;
        for (int j = 0; j < NTOK; ++j) Sc[j] *= rs;
    }
    __syncthreads();

    // PV: 81 rows x 8 chunks, vectorized accumulate + store
    for (int idx = t; idx < NTOK * 8; idx += 256) {
        int r = idx >> 3, c8 = (idx & 7) * 8;
        float acc[8];
#pragma unroll
        for (int q = 0; q < 8; ++q) acc[q] = 0.f;
        if (r == 0) {
            for (int j = 0; j < NTOK; ++j) {
                float w = Sc[j];
                bf16x8 vv = *(const bf16x8*)&Vs[j][c8];
#pragma unroll
                for (int q = 0; q < 8; ++q) acc[q] += w * (float)vv[q];
            }
        } else {
            int qi = r - 1, fb = (qi / 20) * 20;
            {
                float w = S[qi][0];
                bf16x8 vv = *(const bf16x8*)&Vs[0][c8];
#pragma unroll
                for (int q = 0; q < 8; ++q) acc[q] += w * (float)vv[q];
            }
            for (int j = 1; j < 21; ++j) {
                float w = S[qi][j];
                bf16x8 vv = *(const bf16x8*)&Vs[fb + j][c8];
#pragma unroll
                for (int q = 0; q < 8; ++q) acc[q] += w * (float)vv[q];
            }
        }
        bf16 ob[8];
#pragma unroll
        for (int q = 0; q < 8; ++q) ob[q] = (bf16)acc[q];
        *(uint4*)&aout[(size_t)(b * NTOK + r) * EMBED + h * 64 + c8] = *(const uint4*)ob;
    }
}

// ---------------------------------------------------------------------------
extern "C" void kernel_launch(void* const* d_in, const int* in_sizes, int n_in,
                              void* d_out, int out_size, void* d_ws, size_t ws_size,
                              hipStream_t stream) {
    const float* x = (const float*)d_in[0];
    const int* xmask = (const int*)d_in[1];
    const float* objW = (const float*)d_in[2];
    const float* objb = (const float*)d_in[3];
    const float* posW = (const float*)d_in[4];
    const float* posb = (const float*)d_in[5];
    const float* clsT = (const float*)d_in[6];
    const float* clsP = (const float*)d_in[7];
    const float* temb = (const float*)d_in[8];
    const float* ln1w = (const float*)d_in[9];
    const float* ln1b = (const float*)d_in[10];
    const float* ln2w = (const float*)d_in[11];
    const float* ln2b = (const float*)d_in[12];
    const float* qkvW = (const float*)d_in[13];
    const float* qkvb = (const float*)d_in[14];
    const float* apW = (const float*)d_in[15];
    const float* apb = (const float*)d_in[16];
    const float* f1W = (const float*)d_in[17];
    const float* f1b = (const float*)d_in[18];
    const float* f2W = (const float*)d_in[19];
    const float* f2b = (const float*)d_in[20];
    const float* projW = (const float*)d_in[21];

    char* ws = (char*)d_ws;
    bf16* tok = (bf16*)(ws);                              // 30.4 MiB
    bf16* s1 = (bf16*)(ws + (size_t)(32 << 20));          // 30.4 MiB (ln out / attn out)
    float* mb = (float*)(ws + (size_t)(64 << 20));        // 83 KB
    bf16* big = (bf16*)(ws + (size_t)(65 << 20));         // up to 121.5 MiB (xr/qkv/hidden)
    float* out0 = (float*)d_out;
    float* out1 = out0 + (size_t)ROWS * 256;

    // bf16 weight cache layout (starts above `big`'s end at ~186.5 MiB)
    const size_t WOFF = (size_t)192 << 20;
    const size_t E_OBJ = (size_t)768 * 2048;          //  1,572,864
    const size_t E_QKV = (size_t)DEPTH * 2304 * 768;  // 21,233,664
    const size_t E_AP = (size_t)DEPTH * 768 * 768;    //  7,077,888
    const size_t E_FC = (size_t)DEPTH * 3072 * 768;   // 28,311,552 (fc1 and fc2)
    const size_t E_PROJ = (size_t)256 * 768;          //    196,608
    const size_t WTOT = (E_OBJ + E_QKV + E_AP + 2 * E_FC + E_PROJ) * 2;
    const bool bigws = ws_size >= WOFF + WTOT;

    if (bigws) {
        bf16* objW16 = (bf16*)(ws + WOFF);
        bf16* qkvW16 = objW16 + E_OBJ;
        bf16* apW16 = qkvW16 + E_QKV;
        bf16* fc1W16 = apW16 + E_AP;
        bf16* fc2W16 = fc1W16 + E_FC;
        bf16* projW16 = fc2W16 + E_FC;

        // one-shot weight conversion (grid = elems/2048, all exact)
        w2bf_kernel<<<(int)(E_OBJ / 2048), 256, 0, stream>>>(objW, objW16);
        w2bf_kernel<<<(int)(E_QKV / 2048), 256, 0, stream>>>(qkvW, qkvW16);
        w2bf_kernel<<<(int)(E_AP / 2048), 256, 0, stream>>>(apW, apW16);
        w2bf_kernel<<<(int)(E_FC / 2048), 256, 0, stream>>>(f1W, fc1W16);
        w2bf_kernel<<<(int)(E_FC / 2048), 256, 0, stream>>>(f2W, fc2W16);
        w2bf_kernel<<<(int)(E_PROJ / 2048), 256, 0, stream>>>(projW, projW16);

        // Embedding
        repack_kernel<<<SROWS, 256, 0, stream>>>(x, big);
        gemm_bb<0, true, bf16><<<dim3(EMBED / 128, SROWS / 128), 256, 0, stream>>>(
            big, 2048, objW16, objb, nullptr, tok, EMBED, 2048);
        embed_finish<<<SROWS, 256, 0, stream>>>(x, posW, posb, temb, tok);
        cls_mbias_kernel<<<B_, 256, 0, stream>>>(clsT, clsP, xmask, tok, mb, out1);

        // Transformer layers
        for (int l = 0; l < DEPTH; ++l) {
            ln_kernel<<<ROWS, 256, 0, stream>>>(tok, ln1w + l * EMBED, ln1b + l * EMBED, s1);
            gemm_bb<0, false, bf16><<<dim3(2304 / 128, ROWS / 128), 256, 0, stream>>>(
                s1, EMBED, qkvW16 + (size_t)l * 2304 * 768, qkvb + l * 2304, nullptr, big,
                2304, EMBED);
            attn_kernel<<<B_ * HEADS, 256, 0, stream>>>(big, mb, s1);
            gemm_bb<2, false, bf16><<<dim3(EMBED / 128, ROWS / 128), 256, 0, stream>>>(
                s1, EMBED, apW16 + (size_t)l * 768 * 768, apb + l * EMBED, tok, tok, EMBED,
                EMBED);
            ln_kernel<<<ROWS, 256, 0, stream>>>(tok, ln2w + l * EMBED, ln2b + l * EMBED, s1);
            gemm_bb<1, false, bf16><<<dim3(3072 / 128, ROWS / 128), 256, 0, stream>>>(
                s1, EMBED, fc1W16 + (size_t)l * 3072 * 768, f1b + l * 3072, nullptr, big,
                3072, EMBED);
            gemm_bb<2, false, bf16><<<dim3(EMBED / 128, ROWS / 128), 256, 0, stream>>>(
                big, 3072, fc2W16 + (size_t)l * 3072 * 768, f2b + l * EMBED, tok, tok, EMBED,
                3072);
        }

        // Final projection (no bias), f32 output
        gemm_bb<0, false, float><<<dim3(256 / 128, ROWS / 128), 256, 0, stream>>>(
            tok, EMBED, projW16, nullptr, nullptr, out0, 256, EMBED);
    } else {
        // -------- fallback: f32-weight path --------
        repack_kernel<<<SROWS, 256, 0, stream>>>(x, big);
        gemm_bt<0, true, bf16><<<dim3(SROWS / 128, EMBED / 128), 256, 0, stream>>>(
            big, 2048, objW, objb, nullptr, tok, EMBED, 2048);
        embed_finish<<<SROWS, 256, 0, stream>>>(x, posW, posb, temb, tok);
        cls_mbias_kernel<<<B_, 256, 0, stream>>>(clsT, clsP, xmask, tok, mb, out1);

        for (int l = 0; l < DEPTH; ++l) {
            ln_kernel<<<ROWS, 256, 0, stream>>>(tok, ln1w + l * EMBED, ln1b + l * EMBED, s1);
            gemm_bt<0, false, bf16><<<dim3(ROWS / 128, 2304 / 128), 256, 0, stream>>>(
                s1, EMBED, qkvW + (size_t)l * 2304 * EMBED, qkvb + l * 2304, nullptr, big,
                2304, EMBED);
            attn_kernel<<<B_ * HEADS, 256, 0, stream>>>(big, mb, s1);
            gemm_bt<2, false, bf16><<<dim3(ROWS / 128, EMBED / 128), 256, 0, stream>>>(
                s1, EMBED, apW + (size_t)l * EMBED * EMBED, apb + l * EMBED, tok, tok, EMBED,
                EMBED);
            ln_kernel<<<ROWS, 256, 0, stream>>>(tok, ln2w + l * EMBED, ln2b + l * EMBED, s1);
            gemm_bt<1, false, bf16><<<dim3(ROWS / 128, 3072 / 128), 256, 0, stream>>>(
                s1, EMBED, f1W + (size_t)l * 3072 * EMBED, f1b + l * 3072, nullptr, big, 3072,
                EMBED);
            gemm_bt<2, false, bf16><<<dim3(ROWS / 128, EMBED / 128), 256, 0, stream>>>(
                big, 3072, f2W + (size_t)l * EMBED * 3072, f2b + l * EMBED, tok, tok, EMBED,
                3072);
        }

        gemm_bt<0, false, float><<<dim3(ROWS / 128, 256 / 128), 256, 0, stream>>>(
            tok, EMBED, projW, nullptr, nullptr, out0, 256, EMBED);
    }
}

// Round 4
// 7405.681 us; speedup vs baseline: 1.4183x; 1.0198x over previous
//
#include <hip/hip_runtime.h>

typedef __bf16 bf16;
typedef __bf16 bf16x8 __attribute__((ext_vector_type(8)));
typedef float f32x4 __attribute__((ext_vector_type(4)));

#define EMBED 768
#define HEADS 12
#define DEPTH 12
#define B_ 256
#define F_ 4
#define L_ 20
#define NTOK 81              // 1 + F_*L_
#define ROWS (B_ * NTOK)     // 20736
#define SROWS (B_ * F_ * L_) // 20480

// async global->LDS, 16B per lane; LDS dst is wave-uniform base + lane*16
#define GLOAD16(g, l)                                                              \
    __builtin_amdgcn_global_load_lds((const __attribute__((address_space(1))) void*)(g), \
                                     (__attribute__((address_space(3))) void*)(l), 16, 0, 0)

// Fast exact-gelu: Abramowitz-Stegun 7.1.26 erf, |err| <= 1.5e-7 (<< bf16 ulp)
__device__ __forceinline__ float fast_gelu(float v) {
    float x = v * 0.70710678118654752f;
    float ax = fabsf(x);
    float t = __fdividef(1.f, fmaf(0.3275911f, ax, 1.f));
    float p = ((((1.061405429f * t - 1.453152027f) * t + 1.421413741f) * t -
                0.284496736f) * t + 0.254829592f) * t;
    float e = __expf(-ax * ax);
    float erfv = copysignf(1.f - p * e, x);
    return 0.5f * v * (1.f + erfv);
}

// ---------------------------------------------------------------------------
// Repack + convert x[..., :2048] (f32, lda=2054) -> contiguous bf16 (20480,2048)
// ---------------------------------------------------------------------------
__global__ __launch_bounds__(256) void repack_kernel(const float* __restrict__ x,
                                                     bf16* __restrict__ xr) {
    int row = blockIdx.x;
    const float* src = x + (size_t)row * 2054;
    bf16* dst = xr + (size_t)row * 2048;
    int t = threadIdx.x;
    int e0 = t * 8;
    bf16 tmp[8];
#pragma unroll
    for (int i = 0; i < 4; ++i) {
        float2 v = *(const float2*)&src[e0 + 2 * i];
        tmp[2 * i] = (bf16)v.x;
        tmp[2 * i + 1] = (bf16)v.y;
    }
    *(uint4*)&dst[e0] = *(const uint4*)tmp;
}

// ---------------------------------------------------------------------------
// Weight convert f32 -> bf16, 8 elems/thread
// ---------------------------------------------------------------------------
__global__ __launch_bounds__(256) void w2bf_kernel(const float* __restrict__ src,
                                                   bf16* __restrict__ dst) {
    size_t i = ((size_t)blockIdx.x * 256 + threadIdx.x) * 8;
    float4 a = *(const float4*)&src[i];
    float4 b = *(const float4*)&src[i + 4];
    bf16 t[8] = {(bf16)a.x, (bf16)a.y, (bf16)a.z, (bf16)a.w,
                 (bf16)b.x, (bf16)b.y, (bf16)b.z, (bf16)b.w};
    *(uint4*)&dst[i] = *(const uint4*)t;
}

// ---------------------------------------------------------------------------
// GEMM (bf16 A, bf16 W): C[M,N] = A[M,K] @ W[N,K]^T + bias, fp32 accum.
// m97-structure: BK=64, global_load_lds width-16, XOR-swizzled LDS (swizzle on
// the GLOBAL source address, linear LDS dest, swizzled ds_read). Tile 128x128,
// 256 threads (4 waves, 2x2), mfma_f32_16x16x32_bf16. Bijective XCD-chunked
// block swizzle. Epilogue: per-wave LDS transpose ([16][68] f32 patch, 2-way
// write aliasing = free, uniform b128 re-read) -> coalesced bf16x8 stores.
// FUSE: 0 none, 1 exact-gelu, 2 add residual R(bf16). ROWMAP: skip cls rows.
// ---------------------------------------------------------------------------
template <int FUSE, bool ROWMAP, typename CT>
__global__ __launch_bounds__(256) void gemm_bb(const bf16* __restrict__ A, int lda,
                                               const bf16* __restrict__ W,
                                               const float* __restrict__ bias,
                                               const bf16* __restrict__ R,
                                               CT* __restrict__ C, int N, int K) {
    __shared__ __align__(16) char smem[32768];  // staging: As 16K | Ws 16K; epilogue: 4x4352B

    const int tid = threadIdx.x;
    const int lane = tid & 63;
    const int wv = tid >> 6;
    const int wm = (wv & 1) * 64;
    const int wn = (wv >> 1) * 64;
    const int lr = lane & 15;
    const int lq = lane >> 4;

    // bijective XCD-chunked swizzle: consecutive remapped ids stay on one XCD
    const int GX = gridDim.x;
    const int nwg = GX * gridDim.y;
    const int flat = blockIdx.y * GX + blockIdx.x;
    const int xcd = flat & 7, pos = flat >> 3;
    const int qc = nwg >> 3, rc = nwg & 7;
    const int wg = (xcd < rc ? xcd * (qc + 1) : rc * (qc + 1) + (xcd - rc) * qc) + pos;
    const int n0 = (wg % GX) * 128;
    const int m0 = (wg / GX) * 128;

    // Staging lane geometry. LDS linear offset o = chunk*1024 + lane*16 bytes;
    // row = o>>7, colbyte = o&127. We want LDS[o] = tile[row][colbyte ^ ((row&7)<<4)]
    // so reads at swizzled addresses land conflict-free. row&7 == lane>>3 here.
    const int srow = lane >> 3;                 // row within 8-row chunk
    const int scol = 8 * ((lane & 7) ^ srow);   // pre-swizzled element col
    const bf16* aB = A + (size_t)(m0 + srow) * lda + scol;
    const bf16* wB = W + (size_t)(n0 + srow) * K + scol;

    bf16* As = (bf16*)smem;
    bf16* Ws = (bf16*)(smem + 16384);

    f32x4 acc[4][4];
#pragma unroll
    for (int i = 0; i < 4; ++i)
#pragma unroll
        for (int j = 0; j < 4; ++j) acc[i][j] = (f32x4){0.f, 0.f, 0.f, 0.f};

    const int swz = (lr & 7) << 4;

    for (int k0 = 0; k0 < K; k0 += 64) {
        // 16 chunks of 1KB per tile; wave wv stages chunks [wv*4, wv*4+4) of each
#pragma unroll
        for (int i = 0; i < 4; ++i) {
            const int ch = wv * 4 + i;
            GLOAD16(aB + (size_t)(ch * 8) * lda + k0, smem + ch * 1024);
            GLOAD16(wB + (size_t)(ch * 8) * K + k0, smem + 16384 + ch * 1024);
        }
        __syncthreads();  // compiler emits vmcnt(0) drain before s_barrier
#pragma unroll
        for (int kk = 0; kk < 2; ++kk) {
            // swizzled read: colbyte = (kk*64 | lq*16) ^ ((row&7)<<4); row&7 == lr&7
            const int co = (((kk << 6) | (lq << 4)) ^ swz) >> 1;
            bf16x8 af[4], bw[4];
#pragma unroll
            for (int t = 0; t < 4; ++t) {
                af[t] = *(const bf16x8*)&As[(wm + t * 16 + lr) * 64 + co];
                bw[t] = *(const bf16x8*)&Ws[(wn + t * 16 + lr) * 64 + co];
            }
#pragma unroll
            for (int mi = 0; mi < 4; ++mi)
#pragma unroll
                for (int ni = 0; ni < 4; ++ni)
                    acc[mi][ni] = __builtin_amdgcn_mfma_f32_16x16x32_bf16(af[mi], bw[ni],
                                                                          acc[mi][ni], 0, 0, 0);
        }
        __syncthreads();
    }

    // ---- epilogue: per-wave LDS transpose -> coalesced vector IO ----
    // safe: after the final barrier above, all waves are done reading As/Ws.
    float* patch = (float*)(smem + wv * 4352);  // [16][68] f32, wave-private
    float bv4[4];
#pragma unroll
    for (int ni = 0; ni < 4; ++ni) bv4[ni] = bias ? bias[n0 + wn + ni * 16 + lr] : 0.f;
    const int rr = lane >> 3;
    const int c8 = (lane & 7) * 8;
#pragma unroll
    for (int mi = 0; mi < 4; ++mi) {
#pragma unroll
        for (int ni = 0; ni < 4; ++ni)
#pragma unroll
            for (int r = 0; r < 4; ++r)
                patch[(lq * 4 + r) * 68 + ni * 16 + lr] = acc[mi][ni][r] + bv4[ni];
        // same-wave LDS RAW/WAR ordering is program-order; compiler inserts waits
#pragma unroll
        for (int hf = 0; hf < 2; ++hf) {
            int row = rr + hf * 8;
            float v[8];
            *(float4*)&v[0] = *(const float4*)&patch[row * 68 + c8];
            *(float4*)&v[4] = *(const float4*)&patch[row * 68 + c8 + 4];
            int grow = m0 + wm + mi * 16 + row;
            int gcol = n0 + wn + c8;
            if (FUSE == 1) {
#pragma unroll
                for (int q = 0; q < 8; ++q) v[q] = fast_gelu(v[q]);
            }
            if (FUSE == 2) {
                bf16x8 rv = *(const bf16x8*)&R[(size_t)grow * N + gcol];
#pragma unroll
                for (int q = 0; q < 8; ++q) v[q] += (float)rv[q];
            }
            int orow = grow;
            if (ROWMAP) orow = grow + grow / 80 + 1;  // skip cls rows
            if constexpr (sizeof(CT) == 2) {
                bf16 ob[8];
#pragma unroll
                for (int q = 0; q < 8; ++q) ob[q] = (bf16)v[q];
                *(uint4*)&C[(size_t)orow * N + gcol] = *(const uint4*)ob;
            } else {
                *(float4*)&C[(size_t)orow * N + gcol] = *(const float4*)&v[0];
                *(float4*)&C[(size_t)orow * N + gcol + 4] = *(const float4*)&v[4];
            }
        }
    }
}

// ---------------------------------------------------------------------------
// Fallback GEMM (f32 W converted in-kernel) — used only if workspace too small
// ---------------------------------------------------------------------------
template <int FUSE, bool ROWMAP, typename CT>
__global__ __launch_bounds__(256) void gemm_bt(const bf16* __restrict__ A, int lda,
                                               const float* __restrict__ W,
                                               const float* __restrict__ bias,
                                               const bf16* __restrict__ R,
                                               CT* __restrict__ C, int N, int K) {
    __shared__ __align__(16) bf16 As[128][32];
    __shared__ __align__(16) bf16 Ws[128][32];

    const int tid = threadIdx.x;
    const int lane = tid & 63;
    const int wv = tid >> 6;
    const int wm = (wv & 1) * 64;
    const int wn = (wv >> 1) * 64;
    const int lr = lane & 15;
    const int lq = lane >> 4;
    const int m0 = blockIdx.x * 128;
    const int n0 = blockIdx.y * 128;

    f32x4 acc[4][4];
#pragma unroll
    for (int i = 0; i < 4; ++i)
#pragma unroll
        for (int j = 0; j < 4; ++j) acc[i][j] = (f32x4){0.f, 0.f, 0.f, 0.f};

    for (int k0 = 0; k0 < K; k0 += 32) {
#pragma unroll
        for (int i = 0; i < 2; ++i) {
            int c = tid + 256 * i;
            int row = c >> 2;
            int kc = (c & 3) * 8;
            *(uint4*)&As[row][kc] = *(const uint4*)&A[(size_t)(m0 + row) * lda + k0 + kc];
        }
#pragma unroll
        for (int i = 0; i < 4; ++i) {
            int c = tid + 256 * i;
            int row = c >> 3;
            int kc = (c & 7) * 4;
            float4 v = *(const float4*)&W[(size_t)(n0 + row) * K + k0 + kc];
            bf16 wb[4] = {(bf16)v.x, (bf16)v.y, (bf16)v.z, (bf16)v.w};
            *(uint2*)&Ws[row][kc] = *(const uint2*)wb;
        }
        __syncthreads();
        bf16x8 af[4], bf_[4];
#pragma unroll
        for (int t = 0; t < 4; ++t) {
            af[t] = *(const bf16x8*)&As[wm + t * 16 + lr][lq * 8];
            bf_[t] = *(const bf16x8*)&Ws[wn + t * 16 + lr][lq * 8];
        }
#pragma unroll
        for (int mi = 0; mi < 4; ++mi)
#pragma unroll
            for (int ni = 0; ni < 4; ++ni)
                acc[mi][ni] = __builtin_amdgcn_mfma_f32_16x16x32_bf16(af[mi], bf_[ni],
                                                                      acc[mi][ni], 0, 0, 0);
        __syncthreads();
    }

#pragma unroll
    for (int mi = 0; mi < 4; ++mi) {
#pragma unroll
        for (int ni = 0; ni < 4; ++ni) {
            int gcol = n0 + wn + ni * 16 + lr;
            float bv = bias ? bias[gcol] : 0.f;
#pragma unroll
            for (int r = 0; r < 4; ++r) {
                int grow = m0 + wm + mi * 16 + lq * 4 + r;
                float v = acc[mi][ni][r] + bv;
                if (FUSE == 1) v = fast_gelu(v);
                if (FUSE == 2) v += (float)R[(size_t)grow * N + gcol];
                int orow = grow;
                if (ROWMAP) orow = grow + grow / 80 + 1;
                C[(size_t)orow * N + gcol] = (CT)v;
            }
        }
    }
}

// ---------------------------------------------------------------------------
// Embed finish: add pos (K=6, f32) + pos_b + temporal_embed into tok (bf16)
// ---------------------------------------------------------------------------
__global__ __launch_bounds__(256) void embed_finish(const float* __restrict__ x,
                                                    const float* __restrict__ posW,
                                                    const float* __restrict__ posb,
                                                    const float* __restrict__ temb,
                                                    bf16* __restrict__ tok) {
    int r = blockIdx.x;  // 0..20479
    int fr = (r % 80) / 20;
    int orow = r + r / 80 + 1;
    __shared__ float pf[6];
    if (threadIdx.x < 6) pf[threadIdx.x] = x[(size_t)r * 2054 + 2048 + threadIdx.x];
    __syncthreads();
    int t = threadIdx.x;
#pragma unroll
    for (int i = 0; i < 3; ++i) {
        int c = t + 256 * i;
        float v = posb[c] + temb[fr * EMBED + c];
#pragma unroll
        for (int j = 0; j < 6; ++j) v += pf[j] * posW[c * 6 + j];
        size_t idx = (size_t)orow * EMBED + c;
        tok[idx] = (bf16)((float)tok[idx] + v);
    }
}

// ---------------------------------------------------------------------------
// cls rows (bf16 tok) + mbias (f32 scratch) + output 1 (f32)
// ---------------------------------------------------------------------------
__global__ __launch_bounds__(256) void cls_mbias_kernel(const float* __restrict__ cls_tok,
                                                        const float* __restrict__ cls_pos,
                                                        const int* __restrict__ xmask,
                                                        bf16* __restrict__ tok,
                                                        float* __restrict__ mbias,
                                                        float* __restrict__ out1) {
    int b = blockIdx.x;
    int t = threadIdx.x;
#pragma unroll
    for (int i = 0; i < 3; ++i) {
        int c = t + 256 * i;
        tok[(size_t)(b * NTOK) * EMBED + c] = (bf16)(cls_tok[c] + cls_pos[c]);
    }
    if (t < NTOK) {
        float mv = (t == 0) ? 0.f : ((float)xmask[b * 80 + t - 1] - 1.f) * 100.f;
        mbias[b * NTOK + t] = mv;
        out1[b * NTOK + t] = mv;
    }
}

// ---------------------------------------------------------------------------
// LayerNorm: 2 rows per block (threads 0-127 -> row0, 128-255 -> row1; 96
// active lanes per row own one bf16x8 chunk each). fp32 stats, eps=1e-6.
// ---------------------------------------------------------------------------
__global__ __launch_bounds__(256) void ln_kernel(const bf16* __restrict__ X,
                                                 const float* __restrict__ w,
                                                 const float* __restrict__ b,
                                                 bf16* __restrict__ Y) {
    int half = threadIdx.x >> 7;           // 0 or 1
    int row = blockIdx.x * 2 + half;
    int tt = threadIdx.x & 127;            // 0..127; active tt<96
    float xv[8];
    float s = 0.f, ss = 0.f;
    if (tt < 96) {
        bf16x8 v8 = *(const bf16x8*)&X[(size_t)row * EMBED + tt * 8];
#pragma unroll
        for (int i = 0; i < 8; ++i) {
            float v = (float)v8[i];
            xv[i] = v;
            s += v;
            ss += v * v;
        }
    }
#pragma unroll
    for (int off = 32; off; off >>= 1) {
        s += __shfl_down(s, off);
        ss += __shfl_down(ss, off);
    }
    __shared__ float ws_s[4], ws_q[4];
    int wv = threadIdx.x >> 6, lane = threadIdx.x & 63;
    if (lane == 0) { ws_s[wv] = s; ws_q[wv] = ss; }
    __syncthreads();
    s = ws_s[half * 2] + ws_s[half * 2 + 1];
    ss = ws_q[half * 2] + ws_q[half * 2 + 1];
    float mean = s * (1.f / 768.f);
    float var = ss * (1.f / 768.f) - mean * mean;
    float inv = rsqrtf(fmaxf(var, 0.f) + 1e-6f);
    if (tt < 96) {
        float4 w0 = *(const float4*)&w[tt * 8];
        float4 w1 = *(const float4*)&w[tt * 8 + 4];
        float4 b0 = *(const float4*)&b[tt * 8];
        float4 b1 = *(const float4*)&b[tt * 8 + 4];
        float wr[8] = {w0.x, w0.y, w0.z, w0.w, w1.x, w1.y, w1.z, w1.w};
        float br[8] = {b0.x, b0.y, b0.z, b0.w, b1.x, b1.y, b1.z, b1.w};
        bf16 ob[8];
#pragma unroll
        for (int i = 0; i < 8; ++i) ob[i] = (bf16)((xv[i] - mean) * inv * wr[i] + br[i]);
        *(uint4*)&Y[(size_t)row * EMBED + tt * 8] = *(const uint4*)ob;
    }
}

// ---------------------------------------------------------------------------
// Frame-local attention. One block per (batch, head). N=81, d=64, f=4, n=20.
// ---------------------------------------------------------------------------
__global__ __launch_bounds__(256) void attn_kernel(const bf16* __restrict__ qkv,
                                                   const float* __restrict__ mbias,
                                                   bf16* __restrict__ aout) {
    int bh = blockIdx.x;
    int b = bh / HEADS, h = bh % HEADS;
    __shared__ __align__(16) float Qf[NTOK][68];
    __shared__ __align__(16) float Kf[NTOK][68];
    __shared__ __align__(16) bf16 Vs[NTOK][72];
    __shared__ float S[80][22];
    __shared__ float Sc[96];
    __shared__ float MB[NTOK];
    const size_t base = (size_t)(b * NTOK) * 2304 + h * 64;
    int t = threadIdx.x;

    // stage: 81 rows x 8 chunks of 8 elems
    for (int ch = t; ch < NTOK * 8; ch += 256) {
        int r = ch >> 3, c8 = (ch & 7) * 8;
        size_t o = base + (size_t)r * 2304 + c8;
        bf16x8 qv = *(const bf16x8*)&qkv[o];
        bf16x8 kv = *(const bf16x8*)&qkv[o + 768];
        *(uint4*)&Vs[r][c8] = *(const uint4*)&qkv[o + 1536];
        float4 q0 = {(float)qv[0], (float)qv[1], (float)qv[2], (float)qv[3]};
        float4 q1 = {(float)qv[4], (float)qv[5], (float)qv[6], (float)qv[7]};
        float4 k0 = {(float)kv[0], (float)kv[1], (float)kv[2], (float)kv[3]};
        float4 k1 = {(float)kv[4], (float)kv[5], (float)kv[6], (float)kv[7]};
        *(float4*)&Qf[r][c8] = q0;
        *(float4*)&Qf[r][c8 + 4] = q1;
        *(float4*)&Kf[r][c8] = k0;
        *(float4*)&Kf[r][c8 + 4] = k1;
    }
    if (t < NTOK) MB[t] = mbias[b * NTOK + t];
    __syncthreads();

    // QK^T. threads 0..239: spatial (3 threads per q-row, 7 keys each);
    // threads 240..255: cls row (16 threads, ~5-6 keys each).
    {
        int qt;
        if (t < 240) {
            qt = 1 + t / 3;
        } else {
            qt = 0;
        }
        float fq[64];
#pragma unroll
        for (int i = 0; i < 16; ++i) {
            float4 v = *(const float4*)&Qf[qt][i * 4];
            fq[4 * i] = v.x; fq[4 * i + 1] = v.y; fq[4 * i + 2] = v.z; fq[4 * i + 3] = v.w;
        }
        if (t < 240) {
            int qi = t / 3, fb = (qi / 20) * 20, kst = t - qi * 3;
            for (int kj = kst; kj < 21; kj += 3) {
                int kt = (kj == 0) ? 0 : fb + kj;
                float acc = 0.f;
#pragma unroll
                for (int i = 0; i < 16; ++i) {
                    float4 kv = *(const float4*)&Kf[kt][i * 4];
                    acc += fq[4 * i] * kv.x + fq[4 * i + 1] * kv.y +
                           fq[4 * i + 2] * kv.z + fq[4 * i + 3] * kv.w;
                }
                S[qi][kj] = acc * 0.125f + MB[kt];
            }
        } else {
            for (int kt = t - 240; kt < NTOK; kt += 16) {
                float acc = 0.f;
#pragma unroll
                for (int i = 0; i < 16; ++i) {
                    float4 kv = *(const float4*)&Kf[kt][i * 4];
                    acc += fq[4 * i] * kv.x + fq[4 * i + 1] * kv.y +
                           fq[4 * i + 2] * kv.z + fq[4 * i + 3] * kv.w;
                }
                Sc[kt] = acc * 0.125f + MB[kt];
            }
        }
    }
    __syncthreads();

    if (t < 80) {
        float mx = -1e30f;
        for (int j = 0; j < 21; ++j) mx = fmaxf(mx, S[t][j]);
        float sum = 0.f;
        for (int j = 0; j < 21; ++j) { float e = __expf(S[t][j] - mx); S[t][j] = e; sum += e; }
        float rs = 1.f / sum;
        for (int j = 0; j < 21; ++j) S[t][j] *= rs;
    } else if (t == 80) {
        float mx = -1e30f;
        for (int j = 0; j < NTOK; ++j) mx = fmaxf(mx, Sc[j]);
        float sum = 0.f;
        for (int j = 0; j < NTOK; ++j) { float e = __expf(Sc[j] - mx); Sc[j] = e; sum += e; }
        float rs = 1.f / sum;
        for (int j = 0; j < NTOK; ++j) Sc[j] *= rs;
    }
    __syncthreads();

    // PV: 81 rows x 8 chunks, vectorized accumulate + store
    for (int idx = t; idx < NTOK * 8; idx += 256) {
        int r = idx >> 3, c8 = (idx & 7) * 8;
        float acc[8];
#pragma unroll
        for (int q = 0; q < 8; ++q) acc[q] = 0.f;
        if (r == 0) {
            for (int j = 0; j < NTOK; ++j) {
                float w = Sc[j];
                bf16x8 vv = *(const bf16x8*)&Vs[j][c8];
#pragma unroll
                for (int q = 0; q < 8; ++q) acc[q] += w * (float)vv[q];
            }
        } else {
            int qi = r - 1, fb = (qi / 20) * 20;
            {
                float w = S[qi][0];
                bf16x8 vv = *(const bf16x8*)&Vs[0][c8];
#pragma unroll
                for (int q = 0; q < 8; ++q) acc[q] += w * (float)vv[q];
            }
            for (int j = 1; j < 21; ++j) {
                float w = S[qi][j];
                bf16x8 vv = *(const bf16x8*)&Vs[fb + j][c8];
#pragma unroll
                for (int q = 0; q < 8; ++q) acc[q] += w * (float)vv[q];
            }
        }
        bf16 ob[8];
#pragma unroll
        for (int q = 0; q < 8; ++q) ob[q] = (bf16)acc[q];
        *(uint4*)&aout[(size_t)(b * NTOK + r) * EMBED + h * 64 + c8] = *(const uint4*)ob;
    }
}

// ---------------------------------------------------------------------------
extern "C" void kernel_launch(void* const* d_in, const int* in_sizes, int n_in,
                              void* d_out, int out_size, void* d_ws, size_t ws_size,
                              hipStream_t stream) {
    const float* x = (const float*)d_in[0];
    const int* xmask = (const int*)d_in[1];
    const float* objW = (const float*)d_in[2];
    const float* objb = (const float*)d_in[3];
    const float* posW = (const float*)d_in[4];
    const float* posb = (const float*)d_in[5];
    const float* clsT = (const float*)d_in[6];
    const float* clsP = (const float*)d_in[7];
    const float* temb = (const float*)d_in[8];
    const float* ln1w = (const float*)d_in[9];
    const float* ln1b = (const float*)d_in[10];
    const float* ln2w = (const float*)d_in[11];
    const float* ln2b = (const float*)d_in[12];
    const float* qkvW = (const float*)d_in[13];
    const float* qkvb = (const float*)d_in[14];
    const float* apW = (const float*)d_in[15];
    const float* apb = (const float*)d_in[16];
    const float* f1W = (const float*)d_in[17];
    const float* f1b = (const float*)d_in[18];
    const float* f2W = (const float*)d_in[19];
    const float* f2b = (const float*)d_in[20];
    const float* projW = (const float*)d_in[21];

    char* ws = (char*)d_ws;
    bf16* tok = (bf16*)(ws);                              // 30.4 MiB
    bf16* s1 = (bf16*)(ws + (size_t)(32 << 20));          // 30.4 MiB (ln out / attn out)
    float* mb = (float*)(ws + (size_t)(64 << 20));        // 83 KB
    bf16* big = (bf16*)(ws + (size_t)(65 << 20));         // up to 121.5 MiB (xr/qkv/hidden)
    float* out0 = (float*)d_out;
    float* out1 = out0 + (size_t)ROWS * 256;

    // bf16 weight cache layout (starts above `big`'s end at ~186.5 MiB)
    const size_t WOFF = (size_t)192 << 20;
    const size_t E_OBJ = (size_t)768 * 2048;          //  1,572,864
    const size_t E_QKV = (size_t)DEPTH * 2304 * 768;  // 21,233,664
    const size_t E_AP = (size_t)DEPTH * 768 * 768;    //  7,077,888
    const size_t E_FC = (size_t)DEPTH * 3072 * 768;   // 28,311,552 (fc1 and fc2)
    const size_t E_PROJ = (size_t)256 * 768;          //    196,608
    const size_t WTOT = (E_OBJ + E_QKV + E_AP + 2 * E_FC + E_PROJ) * 2;
    const bool bigws = ws_size >= WOFF + WTOT;

    if (bigws) {
        bf16* objW16 = (bf16*)(ws + WOFF);
        bf16* qkvW16 = objW16 + E_OBJ;
        bf16* apW16 = qkvW16 + E_QKV;
        bf16* fc1W16 = apW16 + E_AP;
        bf16* fc2W16 = fc1W16 + E_FC;
        bf16* projW16 = fc2W16 + E_FC;

        // one-shot weight conversion (grid = elems/2048, all exact)
        w2bf_kernel<<<(int)(E_OBJ / 2048), 256, 0, stream>>>(objW, objW16);
        w2bf_kernel<<<(int)(E_QKV / 2048), 256, 0, stream>>>(qkvW, qkvW16);
        w2bf_kernel<<<(int)(E_AP / 2048), 256, 0, stream>>>(apW, apW16);
        w2bf_kernel<<<(int)(E_FC / 2048), 256, 0, stream>>>(f1W, fc1W16);
        w2bf_kernel<<<(int)(E_FC / 2048), 256, 0, stream>>>(f2W, fc2W16);
        w2bf_kernel<<<(int)(E_PROJ / 2048), 256, 0, stream>>>(projW, projW16);

        // Embedding
        repack_kernel<<<SROWS, 256, 0, stream>>>(x, big);
        gemm_bb<0, true, bf16><<<dim3(EMBED / 128, SROWS / 128), 256, 0, stream>>>(
            big, 2048, objW16, objb, nullptr, tok, EMBED, 2048);
        embed_finish<<<SROWS, 256, 0, stream>>>(x, posW, posb, temb, tok);
        cls_mbias_kernel<<<B_, 256, 0, stream>>>(clsT, clsP, xmask, tok, mb, out1);

        // Transformer layers
        for (int l = 0; l < DEPTH; ++l) {
            ln_kernel<<<ROWS / 2, 256, 0, stream>>>(tok, ln1w + l * EMBED, ln1b + l * EMBED, s1);
            gemm_bb<0, false, bf16><<<dim3(2304 / 128, ROWS / 128), 256, 0, stream>>>(
                s1, EMBED, qkvW16 + (size_t)l * 2304 * 768, qkvb + l * 2304, nullptr, big,
                2304, EMBED);
            attn_kernel<<<B_ * HEADS, 256, 0, stream>>>(big, mb, s1);
            gemm_bb<2, false, bf16><<<dim3(EMBED / 128, ROWS / 128), 256, 0, stream>>>(
                s1, EMBED, apW16 + (size_t)l * 768 * 768, apb + l * EMBED, tok, tok, EMBED,
                EMBED);
            ln_kernel<<<ROWS / 2, 256, 0, stream>>>(tok, ln2w + l * EMBED, ln2b + l * EMBED, s1);
            gemm_bb<1, false, bf16><<<dim3(3072 / 128, ROWS / 128), 256, 0, stream>>>(
                s1, EMBED, fc1W16 + (size_t)l * 3072 * 768, f1b + l * 3072, nullptr, big,
                3072, EMBED);
            gemm_bb<2, false, bf16><<<dim3(EMBED / 128, ROWS / 128), 256, 0, stream>>>(
                big, 3072, fc2W16 + (size_t)l * 3072 * 768, f2b + l * EMBED, tok, tok, EMBED,
                3072);
        }

        // Final projection (no bias), f32 output
        gemm_bb<0, false, float><<<dim3(256 / 128, ROWS / 128), 256, 0, stream>>>(
            tok, EMBED, projW16, nullptr, nullptr, out0, 256, EMBED);
    } else {
        // -------- fallback: f32-weight path --------
        repack_kernel<<<SROWS, 256, 0, stream>>>(x, big);
        gemm_bt<0, true, bf16><<<dim3(SROWS / 128, EMBED / 128), 256, 0, stream>>>(
            big, 2048, objW, objb, nullptr, tok, EMBED, 2048);
        embed_finish<<<SROWS, 256, 0, stream>>>(x, posW, posb, temb, tok);
        cls_mbias_kernel<<<B_, 256, 0, stream>>>(clsT, clsP, xmask, tok, mb, out1);

        for (int l = 0; l < DEPTH; ++l) {
            ln_kernel<<<ROWS / 2, 256, 0, stream>>>(tok, ln1w + l * EMBED, ln1b + l * EMBED, s1);
            gemm_bt<0, false, bf16><<<dim3(ROWS / 128, 2304 / 128), 256, 0, stream>>>(
                s1, EMBED, qkvW + (size_t)l * 2304 * EMBED, qkvb + l * 2304, nullptr, big,
                2304, EMBED);
            attn_kernel<<<B_ * HEADS, 256, 0, stream>>>(big, mb, s1);
            gemm_bt<2, false, bf16><<<dim3(ROWS / 128, EMBED / 128), 256, 0, stream>>>(
                s1, EMBED, apW + (size_t)l * EMBED * EMBED, apb + l * EMBED, tok, tok, EMBED,
                EMBED);
            ln_kernel<<<ROWS / 2, 256, 0, stream>>>(tok, ln2w + l * EMBED, ln2b + l * EMBED, s1);
            gemm_bt<1, false, bf16><<<dim3(ROWS / 128, 3072 / 128), 256, 0, stream>>>(
                s1, EMBED, f1W + (size_t)l * 3072 * EMBED, f1b + l * 3072, nullptr, big, 3072,
                EMBED);
            gemm_bt<2, false, bf16><<<dim3(ROWS / 128, EMBED / 128), 256, 0, stream>>>(
                big, 3072, f2W + (size_t)l * EMBED * 3072, f2b + l * EMBED, tok, tok, EMBED,
                3072);
        }

        gemm_bt<0, false, float><<<dim3(ROWS / 128, 256 / 128), 256, 0, stream>>>(
            tok, EMBED, projW, nullptr, nullptr, out0, 256, EMBED);
    }
}

// Round 5
// 6180.255 us; speedup vs baseline: 1.6995x; 1.1983x over previous
//
#include <hip/hip_runtime.h>

typedef __bf16 bf16;
typedef __bf16 bf16x8 __attribute__((ext_vector_type(8)));
typedef float f32x4 __attribute__((ext_vector_type(4)));

#define EMBED 768
#define HEADS 12
#define DEPTH 12
#define B_ 256
#define F_ 4
#define L_ 20
#define NTOK 81              // 1 + F_*L_
#define ROWS (B_ * NTOK)     // 20736
#define SROWS (B_ * F_ * L_) // 20480

// async global->LDS, 16B per lane; LDS dst is wave-uniform base + lane*16
#define GLOAD16(g, l)                                                              \
    __builtin_amdgcn_global_load_lds((const __attribute__((address_space(1))) void*)(g), \
                                     (__attribute__((address_space(3))) void*)(l), 16, 0, 0)

// Fast exact-gelu: Abramowitz-Stegun 7.1.26 erf, |err| <= 1.5e-7 (<< bf16 ulp)
__device__ __forceinline__ float fast_gelu(float v) {
    float x = v * 0.70710678118654752f;
    float ax = fabsf(x);
    float t = __fdividef(1.f, fmaf(0.3275911f, ax, 1.f));
    float p = ((((1.061405429f * t - 1.453152027f) * t + 1.421413741f) * t -
                0.284496736f) * t + 0.254829592f) * t;
    float e = __expf(-ax * ax);
    float erfv = copysignf(1.f - p * e, x);
    return 0.5f * v * (1.f + erfv);
}

// ---------------------------------------------------------------------------
// Repack + convert x[..., :2048] (f32, lda=2054) -> contiguous bf16 (20480,2048)
// ---------------------------------------------------------------------------
__global__ __launch_bounds__(256) void repack_kernel(const float* __restrict__ x,
                                                     bf16* __restrict__ xr) {
    int row = blockIdx.x;
    const float* src = x + (size_t)row * 2054;
    bf16* dst = xr + (size_t)row * 2048;
    int t = threadIdx.x;
    int e0 = t * 8;
    bf16 tmp[8];
#pragma unroll
    for (int i = 0; i < 4; ++i) {
        float2 v = *(const float2*)&src[e0 + 2 * i];
        tmp[2 * i] = (bf16)v.x;
        tmp[2 * i + 1] = (bf16)v.y;
    }
    *(uint4*)&dst[e0] = *(const uint4*)tmp;
}

// ---------------------------------------------------------------------------
// Weight convert f32 -> bf16, 8 elems/thread
// ---------------------------------------------------------------------------
__global__ __launch_bounds__(256) void w2bf_kernel(const float* __restrict__ src,
                                                   bf16* __restrict__ dst) {
    size_t i = ((size_t)blockIdx.x * 256 + threadIdx.x) * 8;
    float4 a = *(const float4*)&src[i];
    float4 b = *(const float4*)&src[i + 4];
    bf16 t[8] = {(bf16)a.x, (bf16)a.y, (bf16)a.z, (bf16)a.w,
                 (bf16)b.x, (bf16)b.y, (bf16)b.z, (bf16)b.w};
    *(uint4*)&dst[i] = *(const uint4*)t;
}

// ---------------------------------------------------------------------------
// gemm_256: 256x256 tile, BK=64, 512 thr (8 waves 2Mx4N), 128KiB dbuf LDS.
// Catalog-minimal 2-phase (T3-min): raw s_barrier, STAGE(next) issued BEFORE
// compute, one vmcnt(0)+barrier per K-step -> loads in flight across compute.
// T5 setprio around MFMA cluster. T2 XOR-swizzle via pre-swizzled global src.
// Epilogue: per-wave LDS transpose -> coalesced vector stores.
// ---------------------------------------------------------------------------
template <int FUSE, bool ROWMAP, typename CT>
__global__ __launch_bounds__(512, 2) void gemm_256(const bf16* __restrict__ A, int lda,
                                                   const bf16* __restrict__ W,
                                                   const float* __restrict__ bias,
                                                   const bf16* __restrict__ R,
                                                   CT* __restrict__ C, int N, int K) {
    // LDS: buffer b at b*65536: A-tile 32KB | B-tile 32KB. 131072 B total.
    __shared__ __align__(16) char smem[131072];

    const int tid = threadIdx.x;
    const int lane = tid & 63;
    const int wv = tid >> 6;          // 0..7
    const int wm = (wv >> 2) * 128;   // wave M-offset: 0/128
    const int wn = (wv & 3) * 64;     // wave N-offset: 0/64/128/192
    const int lr = lane & 15;
    const int lq = lane >> 4;

    // bijective XCD-chunked swizzle
    const int GX = gridDim.x;
    const int nwg = GX * gridDim.y;
    const int flat = blockIdx.y * GX + blockIdx.x;
    const int xcd = flat & 7, pos = flat >> 3;
    const int qc = nwg >> 3, rc = nwg & 7;
    const int wg = (xcd < rc ? xcd * (qc + 1) : rc * (qc + 1) + (xcd - rc) * qc) + pos;
    const int n0 = (wg % GX) * 256;
    const int m0 = (wg / GX) * 256;

    // staging lane geometry (pre-swizzled global source, linear LDS dest):
    // LDS[row][bytecol] = tile[row][bytecol ^ ((row&7)<<4)]
    const int srow = lane >> 3;                 // row within 8-row chunk
    const int scol = 8 * ((lane & 7) ^ srow);   // pre-swizzled element col
    // wave wv stages rows [wv*32, wv*32+32) of A and of B (4 chunks of 8 rows)
    const bf16* aP[4];
    const bf16* wP[4];
#pragma unroll
    for (int i = 0; i < 4; ++i) {
        aP[i] = A + (size_t)(m0 + wv * 32 + i * 8 + srow) * lda + scol;
        wP[i] = W + (size_t)(n0 + wv * 32 + i * 8 + srow) * K + scol;
    }

    f32x4 acc[8][4];
#pragma unroll
    for (int i = 0; i < 8; ++i)
#pragma unroll
        for (int j = 0; j < 4; ++j) acc[i][j] = (f32x4){0.f, 0.f, 0.f, 0.f};

    // swizzled ds_read element offsets within a 64-elem row, kk = 0/1
    const int swz = (lr & 7) << 4;
    const int co0 = (((0 << 6) | (lq << 4)) ^ swz) >> 1;
    const int co1 = (((1 << 6) | (lq << 4)) ^ swz) >> 1;

    const int nk = K >> 6;  // K-steps (>= 12 for all shapes used)

    // prologue: stage K-step 0 into buf0, drain, publish
#pragma unroll
    for (int i = 0; i < 4; ++i) {
        GLOAD16(aP[i], smem + (wv * 4 + i) * 1024);
        GLOAD16(wP[i], smem + 32768 + (wv * 4 + i) * 1024);
    }
    asm volatile("s_waitcnt vmcnt(0)" ::: "memory");
    __builtin_amdgcn_sched_barrier(0);
    __builtin_amdgcn_s_barrier();

    int c = 0;
    for (int t = 0; t < nk; ++t) {
        // issue next K-step's stage into the other buffer (freed by the
        // barrier that ended iteration t-1) BEFORE compute: HBM/L2 latency
        // hides under the 64-MFMA compute phase.
        if (t + 1 < nk) {
            const int koff = (t + 1) << 6;
            char* dst = smem + (c ^ 1) * 65536 + (wv * 4) * 1024;
#pragma unroll
            for (int i = 0; i < 4; ++i) {
                GLOAD16(aP[i] + koff, dst + i * 1024);
                GLOAD16(wP[i] + koff, dst + 32768 + i * 1024);
            }
            __builtin_amdgcn_sched_barrier(0);
        }
        // compute K-step t on buffer c
        {
            const bf16* As_ = (const bf16*)(smem + c * 65536);
            const bf16* Bs_ = (const bf16*)(smem + c * 65536 + 32768);
            bf16x8 bw0[4], bw1[4];
#pragma unroll
            for (int ni = 0; ni < 4; ++ni) {
                const int br = (wn + ni * 16 + lr) * 64;
                bw0[ni] = *(const bf16x8*)&Bs_[br + co0];
                bw1[ni] = *(const bf16x8*)&Bs_[br + co1];
            }
            __builtin_amdgcn_s_setprio(1);
#pragma unroll
            for (int mi = 0; mi < 8; ++mi) {
                const int ar = (wm + mi * 16 + lr) * 64;
                bf16x8 a0 = *(const bf16x8*)&As_[ar + co0];
                bf16x8 a1 = *(const bf16x8*)&As_[ar + co1];
#pragma unroll
                for (int ni = 0; ni < 4; ++ni) {
                    acc[mi][ni] =
                        __builtin_amdgcn_mfma_f32_16x16x32_bf16(a0, bw0[ni], acc[mi][ni], 0, 0, 0);
                    acc[mi][ni] =
                        __builtin_amdgcn_mfma_f32_16x16x32_bf16(a1, bw1[ni], acc[mi][ni], 0, 0, 0);
                }
            }
            __builtin_amdgcn_s_setprio(0);
        }
        if (t + 1 < nk) {
            // retire next buffer's loads (issued above, covered by compute),
            // then publish to all waves. Raw barrier: no compiler vmcnt-0.
            asm volatile("s_waitcnt vmcnt(0)" ::: "memory");
            __builtin_amdgcn_sched_barrier(0);
            __builtin_amdgcn_s_barrier();
        }
        c ^= 1;
    }

    // epilogue: all waves must be past their LDS reads before patches reuse smem
    __builtin_amdgcn_s_barrier();
    float* patch = (float*)(smem + wv * 4352);  // [16][68] f32, wave-private
    float bv4[4];
#pragma unroll
    for (int ni = 0; ni < 4; ++ni) bv4[ni] = bias ? bias[n0 + wn + ni * 16 + lr] : 0.f;
    const int rr = lane >> 3;
    const int c8 = (lane & 7) * 8;
#pragma unroll
    for (int mi = 0; mi < 8; ++mi) {
#pragma unroll
        for (int ni = 0; ni < 4; ++ni)
#pragma unroll
            for (int r = 0; r < 4; ++r)
                patch[(lq * 4 + r) * 68 + ni * 16 + lr] = acc[mi][ni][r] + bv4[ni];
        // same-wave LDS RAW ordering is program-order; compiler inserts waits
#pragma unroll
        for (int hf = 0; hf < 2; ++hf) {
            int row = rr + hf * 8;
            float v[8];
            *(float4*)&v[0] = *(const float4*)&patch[row * 68 + c8];
            *(float4*)&v[4] = *(const float4*)&patch[row * 68 + c8 + 4];
            int grow = m0 + wm + mi * 16 + row;
            int gcol = n0 + wn + c8;
            if (FUSE == 1) {
#pragma unroll
                for (int q = 0; q < 8; ++q) v[q] = fast_gelu(v[q]);
            }
            if (FUSE == 2) {
                bf16x8 rv = *(const bf16x8*)&R[(size_t)grow * N + gcol];
#pragma unroll
                for (int q = 0; q < 8; ++q) v[q] += (float)rv[q];
            }
            int orow = grow;
            if (ROWMAP) orow = grow + grow / 80 + 1;  // skip cls rows
            if constexpr (sizeof(CT) == 2) {
                bf16 ob[8];
#pragma unroll
                for (int q = 0; q < 8; ++q) ob[q] = (bf16)v[q];
                *(uint4*)&C[(size_t)orow * N + gcol] = *(const uint4*)ob;
            } else {
                *(float4*)&C[(size_t)orow * N + gcol] = *(const float4*)&v[0];
                *(float4*)&C[(size_t)orow * N + gcol + 4] = *(const float4*)&v[4];
            }
        }
    }
}

// ---------------------------------------------------------------------------
// gemm_bb: 128x128 m97-structure (kept for proj; verified rounds 1-4)
// ---------------------------------------------------------------------------
template <int FUSE, bool ROWMAP, typename CT>
__global__ __launch_bounds__(256) void gemm_bb(const bf16* __restrict__ A, int lda,
                                               const bf16* __restrict__ W,
                                               const float* __restrict__ bias,
                                               const bf16* __restrict__ R,
                                               CT* __restrict__ C, int N, int K) {
    __shared__ __align__(16) char smem[32768];

    const int tid = threadIdx.x;
    const int lane = tid & 63;
    const int wv = tid >> 6;
    const int wm = (wv & 1) * 64;
    const int wn = (wv >> 1) * 64;
    const int lr = lane & 15;
    const int lq = lane >> 4;

    const int GX = gridDim.x;
    const int nwg = GX * gridDim.y;
    const int flat = blockIdx.y * GX + blockIdx.x;
    const int xcd = flat & 7, pos = flat >> 3;
    const int qc = nwg >> 3, rc = nwg & 7;
    const int wg = (xcd < rc ? xcd * (qc + 1) : rc * (qc + 1) + (xcd - rc) * qc) + pos;
    const int n0 = (wg % GX) * 128;
    const int m0 = (wg / GX) * 128;

    const int srow = lane >> 3;
    const int scol = 8 * ((lane & 7) ^ srow);
    const bf16* aB = A + (size_t)(m0 + srow) * lda + scol;
    const bf16* wB = W + (size_t)(n0 + srow) * K + scol;

    bf16* As = (bf16*)smem;
    bf16* Ws = (bf16*)(smem + 16384);

    f32x4 acc[4][4];
#pragma unroll
    for (int i = 0; i < 4; ++i)
#pragma unroll
        for (int j = 0; j < 4; ++j) acc[i][j] = (f32x4){0.f, 0.f, 0.f, 0.f};

    const int swz = (lr & 7) << 4;

    for (int k0 = 0; k0 < K; k0 += 64) {
#pragma unroll
        for (int i = 0; i < 4; ++i) {
            const int ch = wv * 4 + i;
            GLOAD16(aB + (size_t)(ch * 8) * lda + k0, smem + ch * 1024);
            GLOAD16(wB + (size_t)(ch * 8) * K + k0, smem + 16384 + ch * 1024);
        }
        __syncthreads();
#pragma unroll
        for (int kk = 0; kk < 2; ++kk) {
            const int co = (((kk << 6) | (lq << 4)) ^ swz) >> 1;
            bf16x8 af[4], bw[4];
#pragma unroll
            for (int t = 0; t < 4; ++t) {
                af[t] = *(const bf16x8*)&As[(wm + t * 16 + lr) * 64 + co];
                bw[t] = *(const bf16x8*)&Ws[(wn + t * 16 + lr) * 64 + co];
            }
#pragma unroll
            for (int mi = 0; mi < 4; ++mi)
#pragma unroll
                for (int ni = 0; ni < 4; ++ni)
                    acc[mi][ni] = __builtin_amdgcn_mfma_f32_16x16x32_bf16(af[mi], bw[ni],
                                                                          acc[mi][ni], 0, 0, 0);
        }
        __syncthreads();
    }

    float* patch = (float*)(smem + wv * 4352);
    float bv4[4];
#pragma unroll
    for (int ni = 0; ni < 4; ++ni) bv4[ni] = bias ? bias[n0 + wn + ni * 16 + lr] : 0.f;
    const int rr = lane >> 3;
    const int c8 = (lane & 7) * 8;
#pragma unroll
    for (int mi = 0; mi < 4; ++mi) {
#pragma unroll
        for (int ni = 0; ni < 4; ++ni)
#pragma unroll
            for (int r = 0; r < 4; ++r)
                patch[(lq * 4 + r) * 68 + ni * 16 + lr] = acc[mi][ni][r] + bv4[ni];
#pragma unroll
        for (int hf = 0; hf < 2; ++hf) {
            int row = rr + hf * 8;
            float v[8];
            *(float4*)&v[0] = *(const float4*)&patch[row * 68 + c8];
            *(float4*)&v[4] = *(const float4*)&patch[row * 68 + c8 + 4];
            int grow = m0 + wm + mi * 16 + row;
            int gcol = n0 + wn + c8;
            if (FUSE == 1) {
#pragma unroll
                for (int q = 0; q < 8; ++q) v[q] = fast_gelu(v[q]);
            }
            if (FUSE == 2) {
                bf16x8 rv = *(const bf16x8*)&R[(size_t)grow * N + gcol];
#pragma unroll
                for (int q = 0; q < 8; ++q) v[q] += (float)rv[q];
            }
            int orow = grow;
            if (ROWMAP) orow = grow + grow / 80 + 1;
            if constexpr (sizeof(CT) == 2) {
                bf16 ob[8];
#pragma unroll
                for (int q = 0; q < 8; ++q) ob[q] = (bf16)v[q];
                *(uint4*)&C[(size_t)orow * N + gcol] = *(const uint4*)ob;
            } else {
                *(float4*)&C[(size_t)orow * N + gcol] = *(const float4*)&v[0];
                *(float4*)&C[(size_t)orow * N + gcol + 4] = *(const float4*)&v[4];
            }
        }
    }
}

// ---------------------------------------------------------------------------
// Fallback GEMM (f32 W converted in-kernel) — used only if workspace too small
// ---------------------------------------------------------------------------
template <int FUSE, bool ROWMAP, typename CT>
__global__ __launch_bounds__(256) void gemm_bt(const bf16* __restrict__ A, int lda,
                                               const float* __restrict__ W,
                                               const float* __restrict__ bias,
                                               const bf16* __restrict__ R,
                                               CT* __restrict__ C, int N, int K) {
    __shared__ __align__(16) bf16 As[128][32];
    __shared__ __align__(16) bf16 Ws[128][32];

    const int tid = threadIdx.x;
    const int lane = tid & 63;
    const int wv = tid >> 6;
    const int wm = (wv & 1) * 64;
    const int wn = (wv >> 1) * 64;
    const int lr = lane & 15;
    const int lq = lane >> 4;
    const int m0 = blockIdx.x * 128;
    const int n0 = blockIdx.y * 128;

    f32x4 acc[4][4];
#pragma unroll
    for (int i = 0; i < 4; ++i)
#pragma unroll
        for (int j = 0; j < 4; ++j) acc[i][j] = (f32x4){0.f, 0.f, 0.f, 0.f};

    for (int k0 = 0; k0 < K; k0 += 32) {
#pragma unroll
        for (int i = 0; i < 2; ++i) {
            int c = tid + 256 * i;
            int row = c >> 2;
            int kc = (c & 3) * 8;
            *(uint4*)&As[row][kc] = *(const uint4*)&A[(size_t)(m0 + row) * lda + k0 + kc];
        }
#pragma unroll
        for (int i = 0; i < 4; ++i) {
            int c = tid + 256 * i;
            int row = c >> 3;
            int kc = (c & 7) * 4;
            float4 v = *(const float4*)&W[(size_t)(n0 + row) * K + k0 + kc];
            bf16 wb[4] = {(bf16)v.x, (bf16)v.y, (bf16)v.z, (bf16)v.w};
            *(uint2*)&Ws[row][kc] = *(const uint2*)wb;
        }
        __syncthreads();
        bf16x8 af[4], bf_[4];
#pragma unroll
        for (int t = 0; t < 4; ++t) {
            af[t] = *(const bf16x8*)&As[wm + t * 16 + lr][lq * 8];
            bf_[t] = *(const bf16x8*)&Ws[wn + t * 16 + lr][lq * 8];
        }
#pragma unroll
        for (int mi = 0; mi < 4; ++mi)
#pragma unroll
            for (int ni = 0; ni < 4; ++ni)
                acc[mi][ni] = __builtin_amdgcn_mfma_f32_16x16x32_bf16(af[mi], bf_[ni],
                                                                      acc[mi][ni], 0, 0, 0);
        __syncthreads();
    }

#pragma unroll
    for (int mi = 0; mi < 4; ++mi) {
#pragma unroll
        for (int ni = 0; ni < 4; ++ni) {
            int gcol = n0 + wn + ni * 16 + lr;
            float bv = bias ? bias[gcol] : 0.f;
#pragma unroll
            for (int r = 0; r < 4; ++r) {
                int grow = m0 + wm + mi * 16 + lq * 4 + r;
                float v = acc[mi][ni][r] + bv;
                if (FUSE == 1) v = fast_gelu(v);
                if (FUSE == 2) v += (float)R[(size_t)grow * N + gcol];
                int orow = grow;
                if (ROWMAP) orow = grow + grow / 80 + 1;
                C[(size_t)orow * N + gcol] = (CT)v;
            }
        }
    }
}

// ---------------------------------------------------------------------------
// Embed finish: add pos (K=6, f32) + pos_b + temporal_embed into tok (bf16)
// ---------------------------------------------------------------------------
__global__ __launch_bounds__(256) void embed_finish(const float* __restrict__ x,
                                                    const float* __restrict__ posW,
                                                    const float* __restrict__ posb,
                                                    const float* __restrict__ temb,
                                                    bf16* __restrict__ tok) {
    int r = blockIdx.x;  // 0..20479
    int fr = (r % 80) / 20;
    int orow = r + r / 80 + 1;
    __shared__ float pf[6];
    if (threadIdx.x < 6) pf[threadIdx.x] = x[(size_t)r * 2054 + 2048 + threadIdx.x];
    __syncthreads();
    int t = threadIdx.x;
#pragma unroll
    for (int i = 0; i < 3; ++i) {
        int c = t + 256 * i;
        float v = posb[c] + temb[fr * EMBED + c];
#pragma unroll
        for (int j = 0; j < 6; ++j) v += pf[j] * posW[c * 6 + j];
        size_t idx = (size_t)orow * EMBED + c;
        tok[idx] = (bf16)((float)tok[idx] + v);
    }
}

// ---------------------------------------------------------------------------
// cls rows (bf16 tok) + mbias (f32 scratch) + output 1 (f32)
// ---------------------------------------------------------------------------
__global__ __launch_bounds__(256) void cls_mbias_kernel(const float* __restrict__ cls_tok,
                                                        const float* __restrict__ cls_pos,
                                                        const int* __restrict__ xmask,
                                                        bf16* __restrict__ tok,
                                                        float* __restrict__ mbias,
                                                        float* __restrict__ out1) {
    int b = blockIdx.x;
    int t = threadIdx.x;
#pragma unroll
    for (int i = 0; i < 3; ++i) {
        int c = t + 256 * i;
        tok[(size_t)(b * NTOK) * EMBED + c] = (bf16)(cls_tok[c] + cls_pos[c]);
    }
    if (t < NTOK) {
        float mv = (t == 0) ? 0.f : ((float)xmask[b * 80 + t - 1] - 1.f) * 100.f;
        mbias[b * NTOK + t] = mv;
        out1[b * NTOK + t] = mv;
    }
}

// ---------------------------------------------------------------------------
// LayerNorm: 2 rows per block, 96 active lanes per row own one bf16x8 chunk.
// ---------------------------------------------------------------------------
__global__ __launch_bounds__(256) void ln_kernel(const bf16* __restrict__ X,
                                                 const float* __restrict__ w,
                                                 const float* __restrict__ b,
                                                 bf16* __restrict__ Y) {
    int half = threadIdx.x >> 7;
    int row = blockIdx.x * 2 + half;
    int tt = threadIdx.x & 127;
    float xv[8];
    float s = 0.f, ss = 0.f;
    if (tt < 96) {
        bf16x8 v8 = *(const bf16x8*)&X[(size_t)row * EMBED + tt * 8];
#pragma unroll
        for (int i = 0; i < 8; ++i) {
            float v = (float)v8[i];
            xv[i] = v;
            s += v;
            ss += v * v;
        }
    }
#pragma unroll
    for (int off = 32; off; off >>= 1) {
        s += __shfl_down(s, off);
        ss += __shfl_down(ss, off);
    }
    __shared__ float ws_s[4], ws_q[4];
    int wv = threadIdx.x >> 6, lane = threadIdx.x & 63;
    if (lane == 0) { ws_s[wv] = s; ws_q[wv] = ss; }
    __syncthreads();
    s = ws_s[half * 2] + ws_s[half * 2 + 1];
    ss = ws_q[half * 2] + ws_q[half * 2 + 1];
    float mean = s * (1.f / 768.f);
    float var = ss * (1.f / 768.f) - mean * mean;
    float inv = rsqrtf(fmaxf(var, 0.f) + 1e-6f);
    if (tt < 96) {
        float4 w0 = *(const float4*)&w[tt * 8];
        float4 w1 = *(const float4*)&w[tt * 8 + 4];
        float4 b0 = *(const float4*)&b[tt * 8];
        float4 b1 = *(const float4*)&b[tt * 8 + 4];
        float wr[8] = {w0.x, w0.y, w0.z, w0.w, w1.x, w1.y, w1.z, w1.w};
        float br[8] = {b0.x, b0.y, b0.z, b0.w, b1.x, b1.y, b1.z, b1.w};
        bf16 ob[8];
#pragma unroll
        for (int i = 0; i < 8; ++i) ob[i] = (bf16)((xv[i] - mean) * inv * wr[i] + br[i]);
        *(uint4*)&Y[(size_t)row * EMBED + tt * 8] = *(const uint4*)ob;
    }
}

// ---------------------------------------------------------------------------
// Frame-local attention. One block per (batch, head). N=81, d=64, f=4, n=20.
// ---------------------------------------------------------------------------
__global__ __launch_bounds__(256) void attn_kernel(const bf16* __restrict__ qkv,
                                                   const float* __restrict__ mbias,
                                                   bf16* __restrict__ aout) {
    int bh = blockIdx.x;
    int b = bh / HEADS, h = bh % HEADS;
    __shared__ __align__(16) float Qf[NTOK][68];
    __shared__ __align__(16) float Kf[NTOK][68];
    __shared__ __align__(16) bf16 Vs[NTOK][72];
    __shared__ float S[80][22];
    __shared__ float Sc[96];
    __shared__ float MB[NTOK];
    const size_t base = (size_t)(b * NTOK) * 2304 + h * 64;
    int t = threadIdx.x;

    for (int ch = t; ch < NTOK * 8; ch += 256) {
        int r = ch >> 3, c8 = (ch & 7) * 8;
        size_t o = base + (size_t)r * 2304 + c8;
        bf16x8 qv = *(const bf16x8*)&qkv[o];
        bf16x8 kv = *(const bf16x8*)&qkv[o + 768];
        *(uint4*)&Vs[r][c8] = *(const uint4*)&qkv[o + 1536];
        float4 q0 = {(float)qv[0], (float)qv[1], (float)qv[2], (float)qv[3]};
        float4 q1 = {(float)qv[4], (float)qv[5], (float)qv[6], (float)qv[7]};
        float4 k0 = {(float)kv[0], (float)kv[1], (float)kv[2], (float)kv[3]};
        float4 k1 = {(float)kv[4], (float)kv[5], (float)kv[6], (float)kv[7]};
        *(float4*)&Qf[r][c8] = q0;
        *(float4*)&Qf[r][c8 + 4] = q1;
        *(float4*)&Kf[r][c8] = k0;
        *(float4*)&Kf[r][c8 + 4] = k1;
    }
    if (t < NTOK) MB[t] = mbias[b * NTOK + t];
    __syncthreads();

    {
        int qt = (t < 240) ? 1 + t / 3 : 0;
        float fq[64];
#pragma unroll
        for (int i = 0; i < 16; ++i) {
            float4 v = *(const float4*)&Qf[qt][i * 4];
            fq[4 * i] = v.x; fq[4 * i + 1] = v.y; fq[4 * i + 2] = v.z; fq[4 * i + 3] = v.w;
        }
        if (t < 240) {
            int qi = t / 3, fb = (qi / 20) * 20, kst = t - qi * 3;
            for (int kj = kst; kj < 21; kj += 3) {
                int kt = (kj == 0) ? 0 : fb + kj;
                float acc = 0.f;
#pragma unroll
                for (int i = 0; i < 16; ++i) {
                    float4 kv = *(const float4*)&Kf[kt][i * 4];
                    acc += fq[4 * i] * kv.x + fq[4 * i + 1] * kv.y +
                           fq[4 * i + 2] * kv.z + fq[4 * i + 3] * kv.w;
                }
                S[qi][kj] = acc * 0.125f + MB[kt];
            }
        } else {
            for (int kt = t - 240; kt < NTOK; kt += 16) {
                float acc = 0.f;
#pragma unroll
                for (int i = 0; i < 16; ++i) {
                    float4 kv = *(const float4*)&Kf[kt][i * 4];
                    acc += fq[4 * i] * kv.x + fq[4 * i + 1] * kv.y +
                           fq[4 * i + 2] * kv.z + fq[4 * i + 3] * kv.w;
                }
                Sc[kt] = acc * 0.125f + MB[kt];
            }
        }
    }
    __syncthreads();

    if (t < 80) {
        float mx = -1e30f;
        for (int j = 0; j < 21; ++j) mx = fmaxf(mx, S[t][j]);
        float sum = 0.f;
        for (int j = 0; j < 21; ++j) { float e = __expf(S[t][j] - mx); S[t][j] = e; sum += e; }
        float rs = 1.f / sum;
        for (int j = 0; j < 21; ++j) S[t][j] *= rs;
    } else if (t == 80) {
        float mx = -1e30f;
        for (int j = 0; j < NTOK; ++j) mx = fmaxf(mx, Sc[j]);
        float sum = 0.f;
        for (int j = 0; j < NTOK; ++j) { float e = __expf(Sc[j] - mx); Sc[j] = e; sum += e; }
        float rs = 1.f / sum;
        for (int j = 0; j < NTOK; ++j) Sc[j] *= rs;
    }
    __syncthreads();

    for (int idx = t; idx < NTOK * 8; idx += 256) {
        int r = idx >> 3, c8 = (idx & 7) * 8;
        float acc[8];
#pragma unroll
        for (int q = 0; q < 8; ++q) acc[q] = 0.f;
        if (r == 0) {
            for (int j = 0; j < NTOK; ++j) {
                float w = Sc[j];
                bf16x8 vv = *(const bf16x8*)&Vs[j][c8];
#pragma unroll
                for (int q = 0; q < 8; ++q) acc[q] += w * (float)vv[q];
            }
        } else {
            int qi = r - 1, fb = (qi / 20) * 20;
            {
                float w = S[qi][0];
                bf16x8 vv = *(const bf16x8*)&Vs[0][c8];
#pragma unroll
                for (int q = 0; q < 8; ++q) acc[q] += w * (float)vv[q];
            }
            for (int j = 1; j < 21; ++j) {
                float w = S[qi][j];
                bf16x8 vv = *(const bf16x8*)&Vs[fb + j][c8];
#pragma unroll
                for (int q = 0; q < 8; ++q) acc[q] += w * (float)vv[q];
            }
        }
        bf16 ob[8];
#pragma unroll
        for (int q = 0; q < 8; ++q) ob[q] = (bf16)acc[q];
        *(uint4*)&aout[(size_t)(b * NTOK + r) * EMBED + h * 64 + c8] = *(const uint4*)ob;
    }
}

// ---------------------------------------------------------------------------
extern "C" void kernel_launch(void* const* d_in, const int* in_sizes, int n_in,
                              void* d_out, int out_size, void* d_ws, size_t ws_size,
                              hipStream_t stream) {
    const float* x = (const float*)d_in[0];
    const int* xmask = (const int*)d_in[1];
    const float* objW = (const float*)d_in[2];
    const float* objb = (const float*)d_in[3];
    const float* posW = (const float*)d_in[4];
    const float* posb = (const float*)d_in[5];
    const float* clsT = (const float*)d_in[6];
    const float* clsP = (const float*)d_in[7];
    const float* temb = (const float*)d_in[8];
    const float* ln1w = (const float*)d_in[9];
    const float* ln1b = (const float*)d_in[10];
    const float* ln2w = (const float*)d_in[11];
    const float* ln2b = (const float*)d_in[12];
    const float* qkvW = (const float*)d_in[13];
    const float* qkvb = (const float*)d_in[14];
    const float* apW = (const float*)d_in[15];
    const float* apb = (const float*)d_in[16];
    const float* f1W = (const float*)d_in[17];
    const float* f1b = (const float*)d_in[18];
    const float* f2W = (const float*)d_in[19];
    const float* f2b = (const float*)d_in[20];
    const float* projW = (const float*)d_in[21];

    char* ws = (char*)d_ws;
    bf16* tok = (bf16*)(ws);                              // 30.4 MiB
    bf16* s1 = (bf16*)(ws + (size_t)(32 << 20));          // 30.4 MiB (ln out / attn out)
    float* mb = (float*)(ws + (size_t)(64 << 20));        // 83 KB
    bf16* big = (bf16*)(ws + (size_t)(65 << 20));         // up to 121.5 MiB (xr/qkv/hidden)
    float* out0 = (float*)d_out;
    float* out1 = out0 + (size_t)ROWS * 256;

    const size_t WOFF = (size_t)192 << 20;
    const size_t E_OBJ = (size_t)768 * 2048;
    const size_t E_QKV = (size_t)DEPTH * 2304 * 768;
    const size_t E_AP = (size_t)DEPTH * 768 * 768;
    const size_t E_FC = (size_t)DEPTH * 3072 * 768;
    const size_t E_PROJ = (size_t)256 * 768;
    const size_t WTOT = (E_OBJ + E_QKV + E_AP + 2 * E_FC + E_PROJ) * 2;
    const bool bigws = ws_size >= WOFF + WTOT;

    if (bigws) {
        bf16* objW16 = (bf16*)(ws + WOFF);
        bf16* qkvW16 = objW16 + E_OBJ;
        bf16* apW16 = qkvW16 + E_QKV;
        bf16* fc1W16 = apW16 + E_AP;
        bf16* fc2W16 = fc1W16 + E_FC;
        bf16* projW16 = fc2W16 + E_FC;

        w2bf_kernel<<<(int)(E_OBJ / 2048), 256, 0, stream>>>(objW, objW16);
        w2bf_kernel<<<(int)(E_QKV / 2048), 256, 0, stream>>>(qkvW, qkvW16);
        w2bf_kernel<<<(int)(E_AP / 2048), 256, 0, stream>>>(apW, apW16);
        w2bf_kernel<<<(int)(E_FC / 2048), 256, 0, stream>>>(f1W, fc1W16);
        w2bf_kernel<<<(int)(E_FC / 2048), 256, 0, stream>>>(f2W, fc2W16);
        w2bf_kernel<<<(int)(E_PROJ / 2048), 256, 0, stream>>>(projW, projW16);

        // Embedding (256-tile pipeline GEMM)
        repack_kernel<<<SROWS, 256, 0, stream>>>(x, big);
        gemm_256<0, true, bf16><<<dim3(EMBED / 256, SROWS / 256), 512, 0, stream>>>(
            big, 2048, objW16, objb, nullptr, tok, EMBED, 2048);
        embed_finish<<<SROWS, 256, 0, stream>>>(x, posW, posb, temb, tok);
        cls_mbias_kernel<<<B_, 256, 0, stream>>>(clsT, clsP, xmask, tok, mb, out1);

        // Transformer layers
        for (int l = 0; l < DEPTH; ++l) {
            ln_kernel<<<ROWS / 2, 256, 0, stream>>>(tok, ln1w + l * EMBED, ln1b + l * EMBED, s1);
            gemm_256<0, false, bf16><<<dim3(2304 / 256, ROWS / 256), 512, 0, stream>>>(
                s1, EMBED, qkvW16 + (size_t)l * 2304 * 768, qkvb + l * 2304, nullptr, big,
                2304, EMBED);
            attn_kernel<<<B_ * HEADS, 256, 0, stream>>>(big, mb, s1);
            gemm_256<2, false, bf16><<<dim3(EMBED / 256, ROWS / 256), 512, 0, stream>>>(
                s1, EMBED, apW16 + (size_t)l * 768 * 768, apb + l * EMBED, tok, tok, EMBED,
                EMBED);
            ln_kernel<<<ROWS / 2, 256, 0, stream>>>(tok, ln2w + l * EMBED, ln2b + l * EMBED, s1);
            gemm_256<1, false, bf16><<<dim3(3072 / 256, ROWS / 256), 512, 0, stream>>>(
                s1, EMBED, fc1W16 + (size_t)l * 3072 * 768, f1b + l * 3072, nullptr, big,
                3072, EMBED);
            gemm_256<2, false, bf16><<<dim3(EMBED / 256, ROWS / 256), 512, 0, stream>>>(
                big, 3072, fc2W16 + (size_t)l * 3072 * 768, f2b + l * EMBED, tok, tok, EMBED,
                3072);
        }

        // Final projection (N=256: keep 128-tile for grid width)
        gemm_bb<0, false, float><<<dim3(256 / 128, ROWS / 128), 256, 0, stream>>>(
            tok, EMBED, projW16, nullptr, nullptr, out0, 256, EMBED);
    } else {
        // -------- fallback: f32-weight path --------
        repack_kernel<<<SROWS, 256, 0, stream>>>(x, big);
        gemm_bt<0, true, bf16><<<dim3(SROWS / 128, EMBED / 128), 256, 0, stream>>>(
            big, 2048, objW, objb, nullptr, tok, EMBED, 2048);
        embed_finish<<<SROWS, 256, 0, stream>>>(x, posW, posb, temb, tok);
        cls_mbias_kernel<<<B_, 256, 0, stream>>>(clsT, clsP, xmask, tok, mb, out1);

        for (int l = 0; l < DEPTH; ++l) {
            ln_kernel<<<ROWS / 2, 256, 0, stream>>>(tok, ln1w + l * EMBED, ln1b + l * EMBED, s1);
            gemm_bt<0, false, bf16><<<dim3(ROWS / 128, 2304 / 128), 256, 0, stream>>>(
                s1, EMBED, qkvW + (size_t)l * 2304 * EMBED, qkvb + l * 2304, nullptr, big,
                2304, EMBED);
            attn_kernel<<<B_ * HEADS, 256, 0, stream>>>(big, mb, s1);
            gemm_bt<2, false, bf16><<<dim3(ROWS / 128, EMBED / 128), 256, 0, stream>>>(
                s1, EMBED, apW + (size_t)l * EMBED * EMBED, apb + l * EMBED, tok, tok, EMBED,
                EMBED);
            ln_kernel<<<ROWS / 2, 256, 0, stream>>>(tok, ln2w + l * EMBED, ln2b + l * EMBED, s1);
            gemm_bt<1, false, bf16><<<dim3(ROWS / 128, 3072 / 128), 256, 0, stream>>>(
                s1, EMBED, f1W + (size_t)l * 3072 * EMBED, f1b + l * 3072, nullptr, big, 3072,
                EMBED);
            gemm_bt<2, false, bf16><<<dim3(ROWS / 128, EMBED / 128), 256, 0, stream>>>(
                big, 3072, f2W + (size_t)l * EMBED * 3072, f2b + l * EMBED, tok, tok, EMBED,
                3072);
        }

        gemm_bt<0, false, float><<<dim3(ROWS / 128, 256 / 128), 256, 0, stream>>>(
            tok, EMBED, projW, nullptr, nullptr, out0, 256, EMBED);
    }
}